// Round 5
// baseline (24480.931 us; speedup 1.0000x reference)
//
#include <hip/hip_runtime.h>
#include <cstdint>
#include <cstddef>

// FC_LSTM on MI355X — Round 9: weight-stationary, hidden-sliced scan.
// R5-R8 evidence: per-CU L2 port (~64 B/cyc) streaming 768KB of shared
// weights per step per CU is the wall (12-14K cyc/step); the compiler
// refuses >128 VGPRs for this kernel (R7 spilled, R8 attribute ignored),
// so register-caching is dead.
// NEW DECOMPOSITION: 32 blocks each own hidden slice n in [8k,8k+8) for ALL
// 32 batches. Per-slice weight rows (Wh i/f/o/g + Wci/Wcf/Wco = 28KB) live
// in LDS -> ZERO per-step weight streaming. Per step, blocks exchange
// h (16KB f16) and c_new (16KB f16) through global memory with 2 grid
// barriers (agent-scope atomics; XCD-safe). Barrier counter reset by a tiny
// kernel each launch (graph-replay safe). Exchange buffers overlay the
// WxT4 region (unused in PRE path) -> workspace layout/NEED unchanged.
// All per-row fdot2 orders replicate R5 exactly -> bit-identical output.

typedef unsigned short u16;
typedef unsigned int   u32;
typedef unsigned long long u64;
typedef float  v4f __attribute__((ext_vector_type(4)));
typedef short  v8s __attribute__((ext_vector_type(8)));
typedef _Float16 h2 __attribute__((ext_vector_type(2)));

#define SEQ 2048
#define NB  32
#define HID 256
#define G4  1024
#define FIN 128
#define COFF (2049*NB*HID)   // element offset of memorys half of d_out

// uint4-unit offsets in ws
#define WH4_OFF  0        // [32][1024] : chunk kc (k=8kc..8kc+7), row n
#define WP4_OFF  32768    // [32][512]  : rows = [Wci n | Wcf n+256]
#define WCO4_OFF 49152    // [32][256]
#define WX4_OFF  57344    // [16][1024] (fallback path; overlay for PRE)
#define W4_TOTAL 73728    // uint4 count (1.125 MB)

// exchange overlay inside the WxT4 region (PRE path only; byte offsets)
#define EXB_BYTE  ((size_t)WX4_OFF * 16)
#define GH_BYTE   0          // u16[32][256]            (16 KB)
#define GC_BYTE   16384      // u16[2][32][256]         (32 KB)
#define BAR_BYTE  49152      // u32 barrier counter

#define NBLK 32
#define NSL  8               // hidden slice per block

__device__ __forceinline__ u16 f2bf(float f) {
  u32 u = __builtin_bit_cast(u32, f);
  u32 r = (u + 0x7fffu + ((u >> 16) & 1u)) >> 16;
  return (u16)r;
}
__device__ __forceinline__ u16 f2h_bits(float f) {
  _Float16 h = (_Float16)f;
  return __builtin_bit_cast(u16, h);
}
__device__ __forceinline__ u32 pack2f(float a, float b) {
  u32 lo = f2h_bits(a);
  u32 hi = f2h_bits(b);
  return lo | (hi << 16);
}
__device__ __forceinline__ float fd(u32 w, u32 u, float acc) {
  h2 hw = __builtin_bit_cast(h2, w);
  h2 hu = __builtin_bit_cast(h2, u);
  return __builtin_amdgcn_fdot2(hw, hu, acc, false);
}
__device__ __forceinline__ float sigm(float v) { return 1.f / (1.f + __expf(-v)); }
__device__ __forceinline__ float tanh_fast(float x) {
  float xx = fminf(fmaxf(x, -15.f), 15.f);
  float e = __expf(2.f * xx);
  return (e - 1.f) / (e + 1.f);
}

// ---------------- Phase 0: weight repack (f32 -> f16 x8 chunks) -------------
__global__ __launch_bounds__(256) void prep_weights(
    const float* __restrict__ Wh, const float* __restrict__ Wci,
    const float* __restrict__ Wcf, const float* __restrict__ Wco,
    const float* __restrict__ Wx, uint4* __restrict__ ws4)
{
  int i = blockIdx.x * 256 + threadIdx.x;
  if (i >= W4_TOTAL) return;
  const float* src;
  if (i < WP4_OFF) {                       // WhT4
    int kc = i >> 10, n = i & 1023;
    src = Wh + n*256 + kc*8;
  } else if (i < WCO4_OFF) {               // WpT4
    int l = i - WP4_OFF; int kc = l >> 9, n = l & 511;
    src = ((n < 256) ? (Wci + n*256) : (Wcf + (n-256)*256)) + kc*8;
  } else if (i < WX4_OFF) {                // WcoT4
    int l = i - WCO4_OFF; int kc = l >> 8, n = l & 255;
    src = Wco + n*256 + kc*8;
  } else {                                 // WxT4 (fallback)
    int l = i - WX4_OFF; int kc = l >> 10, n = l & 1023;
    src = Wx + n*128 + kc*8;
  }
  uint4 r;
  r.x = pack2f(src[0], src[1]);
  r.y = pack2f(src[2], src[3]);
  r.z = pack2f(src[4], src[5]);
  r.w = pack2f(src[6], src[7]);
  ws4[i] = r;
}

// ---------------- barrier counter reset (graph-replay safe) -----------------
__global__ void bar_reset(u32* __restrict__ bar) { *bar = 0u; }

// ---------------- Phase 1: xw GEMM (bf16 MFMA, f32 inputs) ------------------
__global__ __launch_bounds__(256) void xw_gemm(
    const float* __restrict__ x, const float* __restrict__ Wx,
    const float* __restrict__ bx, const float* __restrict__ bh,
    u16* __restrict__ xw)
{
  int wave = threadIdx.x >> 6, lane = threadIdx.x & 63;
  int s = lane & 15, q = lane >> 4;
  int mtile = blockIdx.x;              // 0..4095
  int ntile = blockIdx.y * 4 + wave;   // 0..63
  const float* xa = x  + (size_t)(mtile*16 + s) * 128 + q*8;
  const float* wb = Wx + (size_t)(ntile*16 + s) * 128 + q*8;
  v4f acc = {0.f, 0.f, 0.f, 0.f};
#pragma unroll
  for (int ko = 0; ko < 4; ++ko) {
    float4 a0 = *reinterpret_cast<const float4*>(xa + ko*32);
    float4 a1 = *reinterpret_cast<const float4*>(xa + ko*32 + 4);
    float4 b0 = *reinterpret_cast<const float4*>(wb + ko*32);
    float4 b1 = *reinterpret_cast<const float4*>(wb + ko*32 + 4);
    v8s a, b;
    a[0]=(short)f2bf(a0.x); a[1]=(short)f2bf(a0.y); a[2]=(short)f2bf(a0.z); a[3]=(short)f2bf(a0.w);
    a[4]=(short)f2bf(a1.x); a[5]=(short)f2bf(a1.y); a[6]=(short)f2bf(a1.z); a[7]=(short)f2bf(a1.w);
    b[0]=(short)f2bf(b0.x); b[1]=(short)f2bf(b0.y); b[2]=(short)f2bf(b0.z); b[3]=(short)f2bf(b0.w);
    b[4]=(short)f2bf(b1.x); b[5]=(short)f2bf(b1.y); b[6]=(short)f2bf(b1.z); b[7]=(short)f2bf(b1.w);
    acc = __builtin_amdgcn_mfma_f32_16x16x32_bf16(a, b, acc, 0, 0, 0);
  }
  int n = ntile*16 + s;
  float bias = bx[n] + bh[n];
#pragma unroll
  for (int p = 0; p < 4; ++p) {
    int m = mtile*16 + q*4 + p;
    int bb = m >> 11, t = m & 2047;   // r = b*2048 + t
    xw[(size_t)(t*NB + bb) * G4 + n] = f2h_bits(acc[p] + bias);
  }
}

// ---------------- grid barrier (agent scope, monotone target) ---------------
__device__ __forceinline__ void gbar(u32* bar, u32 tgt) {
  __syncthreads();
  if (threadIdx.x == 0) {
    __hip_atomic_fetch_add(bar, 1u, __ATOMIC_ACQ_REL, __HIP_MEMORY_SCOPE_AGENT);
    while (__hip_atomic_load(bar, __ATOMIC_ACQUIRE, __HIP_MEMORY_SCOPE_AGENT) < tgt)
      __builtin_amdgcn_s_sleep(1);
  }
  __syncthreads();
}

// ---------------- Phase 2 (PRE): weight-stationary sliced scan --------------
// 32 blocks; block k owns n in [8k, 8k+8) for ALL 32 batches.
// 512 threads: role = tid>>8 (0: i,f + c_new | 1: o-part,g + z + h_new);
// p = tid&255 -> b = p>>3, j = p&7, n = 8*blockIdx.x + j.
__global__ __launch_bounds__(512) void lstm_scan_p(
    const uint4* __restrict__ ws4, const u16* __restrict__ xw,
    const float* __restrict__ bci, const float* __restrict__ bcf,
    const float* __restrict__ bco, float* __restrict__ out,
    u16* __restrict__ gh, u16* __restrict__ gc, u32* __restrict__ bar)
{
  const int tid  = threadIdx.x;
  const int nb   = blockIdx.x * NSL;
  const int role = tid >> 8;
  const int p    = tid & 255;
  const int b    = p >> 3;
  const int j    = p & 7;
  const int n    = nb + j;

  // weights: [7 types][8 j][33 pitch] uint4 (pad 32->33 kills bank conflicts)
  __shared__ __align__(16) uint4 s_w4[7*8*33];
  __shared__ __align__(16) u16 s_h16[32*264];   // h, pitch 264 u16 (=33 uint4)
  __shared__ __align__(16) u16 s_cA[32*264];    // c ping
  __shared__ __align__(16) u16 s_cB[32*264];    // c pong (zeroed: c_{-1}=0)
  __shared__ float s_i[256], s_f[256], s_g[256], s_op[256], s_cnf[256], s_cst[256];
  __shared__ float s_bci[NSL], s_bcf[NSL], s_bco[NSL];

  const uint4* WhT4  = ws4 + WH4_OFF;
  const uint4* WpT4  = ws4 + WP4_OFF;
  const uint4* WcoT4 = ws4 + WCO4_OFF;

  // ---- load slice weights to LDS (once) ----
  for (int idx = tid; idx < 7*8*32; idx += 512) {
    int type = idx >> 8;          // 0..6
    int jj   = (idx >> 5) & 7;
    int kc   = idx & 31;
    int row  = nb + jj;
    uint4 v;
    if      (type == 0) v = WhT4[kc*1024 + row];         // Wh_i
    else if (type == 1) v = WhT4[kc*1024 + 256 + row];   // Wh_f
    else if (type == 2) v = WpT4[kc*512 + row];          // Wci
    else if (type == 3) v = WpT4[kc*512 + 256 + row];    // Wcf
    else if (type == 4) v = WhT4[kc*1024 + 512 + row];   // Wh_o
    else if (type == 5) v = WhT4[kc*1024 + 768 + row];   // Wh_g
    else                v = WcoT4[kc*256 + row];         // Wco
    s_w4[type*264 + jj*33 + kc] = v;
  }
  if (tid < NSL) {
    s_bci[tid] = bci[nb + tid];
    s_bcf[tid] = bcf[nb + tid];
    s_bco[tid] = bco[nb + tid];
  }
  for (int q = tid; q < 32*264; q += 512) s_cB[q] = 0;   // c_old for step 0
  if (role == 0) {
    s_cst[p] = 0.f;
    __hip_atomic_store(&gh[b*256 + n], (u16)0, __ATOMIC_RELAXED, __HIP_MEMORY_SCOPE_AGENT);
    out[b*HID + n] = 0.f;          // h0
    out[COFF + b*HID + n] = 0.f;   // c0
  }
  gbar(bar, NBLK);   // init barrier: all zeros visible

  const uint4* h4 = (const uint4*)s_h16;
  int csw = 0;

  for (int ts = 0; ts < SEQ; ++ts) {
    u16* c_old16 = csw ? s_cA : s_cB;   // full c_{ts-1} (f16)
    u16* c_new16 = csw ? s_cB : s_cA;   // filled with c_ts after barrier 1
    const uint4* co4 = (const uint4*)c_old16;

    // xw prefetch (cols per R5 role mapping: i/f for role0, o/g for role1)
    const u16* xr = xw + ((size_t)ts*NB + b) * G4;
    u16 xwa = xr[role == 0 ? n       : 512 + n];
    u16 xwb = xr[role == 0 ? 256 + n : 768 + n];

    // (A) gh -> s_h16 (agent loads: cross-XCD coherent)
    for (int q = tid; q < 2048; q += 512) {
      int bb = q >> 6, k64 = q & 63;   // 64 u64 per 256-u16 row
      u64 v = __hip_atomic_load((u64*)gh + q, __ATOMIC_RELAXED, __HIP_MEMORY_SCOPE_AGENT);
      ((u64*)s_h16)[bb*66 + k64] = v;
    }
    __syncthreads();

    // (B) gate dots — R5 order: Wh kc0..31 (x,z->a0; y,w->a1), then
    //     peephole kc0..31 continuing a0,a1 (role0 only); acc=a0+a1; +=xw.
    const uint4* wA = s_w4 + (role ? 4*264 : 0*264) + j*33;   // Wh_i / Wh_o
    float a0 = 0.f, a1 = 0.f;
#pragma unroll 8
    for (int kc = 0; kc < 32; ++kc) {
      uint4 w  = wA[kc];
      uint4 hh = h4[b*33 + kc];
      a0 = fd(w.x, hh.x, a0); a1 = fd(w.y, hh.y, a1);
      a0 = fd(w.z, hh.z, a0); a1 = fd(w.w, hh.w, a1);
    }
    if (role == 0) {
      const uint4* wP = s_w4 + 2*264 + j*33;                  // Wci
#pragma unroll 8
      for (int kc = 0; kc < 32; ++kc) {
        uint4 w  = wP[kc];
        uint4 cc = co4[b*33 + kc];
        a0 = fd(w.x, cc.x, a0); a1 = fd(w.y, cc.y, a1);
        a0 = fd(w.z, cc.z, a0); a1 = fd(w.w, cc.w, a1);
      }
    }
    float accA = a0 + a1;
    accA += (float)__builtin_bit_cast(_Float16, xwa);

    const uint4* wB = s_w4 + (role ? 5*264 : 1*264) + j*33;   // Wh_f / Wh_g
    float b0 = 0.f, b1 = 0.f;
#pragma unroll 8
    for (int kc = 0; kc < 32; ++kc) {
      uint4 w  = wB[kc];
      uint4 hh = h4[b*33 + kc];
      b0 = fd(w.x, hh.x, b0); b1 = fd(w.y, hh.y, b1);
      b0 = fd(w.z, hh.z, b0); b1 = fd(w.w, hh.w, b1);
    }
    if (role == 0) {
      const uint4* wP = s_w4 + 3*264 + j*33;                  // Wcf
#pragma unroll 8
      for (int kc = 0; kc < 32; ++kc) {
        uint4 w  = wP[kc];
        uint4 cc = co4[b*33 + kc];
        b0 = fd(w.x, cc.x, b0); b1 = fd(w.y, cc.y, b1);
        b0 = fd(w.z, cc.z, b0); b1 = fd(w.w, cc.w, b1);
      }
    }
    float accB = b0 + b1;
    accB += (float)__builtin_bit_cast(_Float16, xwb);

    if (role == 0) {
      s_i[p] = sigm(accA + s_bci[j]);
      s_f[p] = sigm(accB + s_bcf[j]);
    } else {
      s_op[p] = accA;               // o pre-activation (bias+peephole later)
      s_g[p]  = tanh_fast(accB);
    }
    __syncthreads();

    // (C) c_new (role0), publish f16 slice
    if (role == 0) {
      float cn = s_f[p]*s_cst[p] + s_i[p]*s_g[p];
      s_cst[p] = cn;
      s_cnf[p] = cn;
      u16 cb = f2h_bits(cn);
      __hip_atomic_store(&gc[(size_t)(ts & 1)*8192 + b*256 + n], cb,
                         __ATOMIC_RELAXED, __HIP_MEMORY_SCOPE_AGENT);
      out[COFF + (size_t)(ts+1)*(NB*HID) + b*HID + n] = cn;
    }
    gbar(bar, (u32)NBLK * (2*ts + 2));

    // (D) gc[ts&1] -> c_new16 (full c_ts; also next step's c_old)
    {
      const u64* gsrc = (const u64*)(gc + (size_t)(ts & 1)*8192);
      for (int q = tid; q < 2048; q += 512) {
        int bb = q >> 6, k64 = q & 63;
        u64 v = __hip_atomic_load((u64*)gsrc + q, __ATOMIC_RELAXED, __HIP_MEMORY_SCOPE_AGENT);
        ((u64*)c_new16)[bb*66 + k64] = v;
      }
    }
    __syncthreads();

    // (E) o-peephole + h_new (role1). z-part order replicates R5 exactly.
    if (role == 1) {
      const uint4* wz  = s_w4 + 6*264 + j*33;                 // Wco
      const uint4* cn4 = (const uint4*)c_new16;
      float zacc[4];
#pragma unroll
      for (int p4 = 0; p4 < 4; ++p4) {
        float z0 = 0.f, z1 = 0.f;
#pragma unroll
        for (int q8 = 0; q8 < 8; ++q8) {
          int kc = p4*8 + q8;
          uint4 w  = wz[kc];
          uint4 cc = cn4[b*33 + kc];
          z0 = fd(w.x, cc.x, z0); z1 = fd(w.y, cc.y, z1);
          z0 = fd(w.z, cc.z, z0); z1 = fd(w.w, cc.w, z1);
        }
        zacc[p4] = z0 + z1;
      }
      float z = zacc[0] + zacc[1] + zacc[2] + zacc[3] + s_op[p] + s_bco[j];
      float o  = sigm(z);
      float hn = o * tanh_fast(s_cnf[p]);
      out[(size_t)(ts+1)*(NB*HID) + b*HID + n] = hn;
      __hip_atomic_store(&gh[b*256 + n], f2h_bits(hn),
                         __ATOMIC_RELAXED, __HIP_MEMORY_SCOPE_AGENT);
    }
    gbar(bar, (u32)NBLK * (2*ts + 3));

    csw ^= 1;
  }
}

// ---------------- fallback (non-PRE) scan: R5 per-batch kernel --------------
__global__ __launch_bounds__(512, 2) void lstm_scan_np(
    const uint4* __restrict__ ws4, const float* __restrict__ x,
    const float* __restrict__ bx, const float* __restrict__ bh,
    const float* __restrict__ bci, const float* __restrict__ bcf,
    const float* __restrict__ bco, float* __restrict__ out)
{
  const int b = blockIdx.x, t = threadIdx.x;
  const uint4* WhT4  = ws4 + WH4_OFF;
  const uint4* WpT4  = ws4 + WP4_OFF;
  const uint4* WcoT4 = ws4 + WCO4_OFF;
  const uint4* WxT4  = ws4 + WX4_OFF;

  __shared__ __align__(16) uint4 s_wco[8192];
  __shared__ __align__(16) float s_i[256], s_f[256], s_g[256], s_op[256];
  __shared__ __align__(16) float s_c[256], s_cn[256], s_z[4][256];
  __shared__ __align__(16) u16 s_hh[256], s_cc[256], s_x[128];
  __shared__ float s_bci[256], s_bcf[256], s_bco[256];

  for (int i = t; i < 8192; i += 512) s_wco[i] = WcoT4[i];
  if (t < 256) {
    s_c[t] = 0.f; s_hh[t] = 0; s_cc[t] = 0;
    s_bci[t] = bci[t]; s_bcf[t] = bcf[t]; s_bco[t] = bco[t];
    out[b*HID + t] = 0.f;
    out[COFF + b*HID + t] = 0.f;
  }
  const int n1 = 512 + t;
  float biasA = bx[t] + bh[t], biasB = bx[n1] + bh[n1];
  __syncthreads();

  for (int ts = 0; ts < SEQ; ++ts) {
    if (t < 128) {
      const float* xr2 = x + (size_t)(b*SEQ + ts) * FIN;
      s_x[t] = f2h_bits(xr2[t]);
    }
    __syncthreads();

    float a0 = 0.f, a1 = 0.f, c0 = 0.f, c1 = 0.f;
#pragma unroll 4
    for (int kc = 0; kc < 32; ++kc) {
      uint4 wA = WhT4[kc*1024 + t];
      uint4 wB = WhT4[kc*1024 + n1];
      uint4 hh = *reinterpret_cast<const uint4*>(&s_hh[8*kc]);
      a0 = fd(wA.x, hh.x, a0); a1 = fd(wA.y, hh.y, a1);
      a0 = fd(wA.z, hh.z, a0); a1 = fd(wA.w, hh.w, a1);
      c0 = fd(wB.x, hh.x, c0); c1 = fd(wB.y, hh.y, c1);
      c0 = fd(wB.z, hh.z, c0); c1 = fd(wB.w, hh.w, c1);
    }
#pragma unroll 4
    for (int kc = 0; kc < 16; ++kc) {
      uint4 wA = WxT4[kc*1024 + t];
      uint4 wB = WxT4[kc*1024 + n1];
      uint4 xx = *reinterpret_cast<const uint4*>(&s_x[8*kc]);
      a0 = fd(wA.x, xx.x, a0); a1 = fd(wA.y, xx.y, a1);
      a0 = fd(wA.z, xx.z, a0); a1 = fd(wA.w, xx.w, a1);
      c0 = fd(wB.x, xx.x, c0); c1 = fd(wB.y, xx.y, c1);
      c0 = fd(wB.z, xx.z, c0); c1 = fd(wB.w, xx.w, c1);
    }
#pragma unroll 4
    for (int kc = 0; kc < 32; ++kc) {
      uint4 w  = WpT4[kc*512 + t];
      uint4 cc = *reinterpret_cast<const uint4*>(&s_cc[8*kc]);
      a0 = fd(w.x, cc.x, a0); a1 = fd(w.y, cc.y, a1);
      a0 = fd(w.z, cc.z, a0); a1 = fd(w.w, cc.w, a1);
    }
    float accA = a0 + a1 + biasA;
    float accB = c0 + c1 + biasB;

    int idx = t & 255;
    if (t < 256) { s_i[idx]  = sigm(accA + s_bci[idx]); s_op[idx] = accB; }
    else         { s_f[idx]  = sigm(accA + s_bcf[idx]); s_g[idx]  = tanh_fast(accB); }
    __syncthreads();

    if (t < 256) {
      float cn = s_f[t]*s_c[t] + s_i[t]*s_g[t];
      s_cn[t] = cn; s_c[t] = cn;
      s_cc[t] = f2h_bits(cn);
      out[COFF + (size_t)(ts+1)*(NB*HID) + b*HID + t] = cn;
    }
    __syncthreads();

    {
      int nn = t & 255, p0 = t >> 8;
      float z0 = 0.f, z1 = 0.f, z2 = 0.f, z3 = 0.f;
#pragma unroll
      for (int q8 = 0; q8 < 8; ++q8) {
        int kc = p0*8 + q8;
        uint4 w  = s_wco[kc*256 + nn];
        uint4 cc = *reinterpret_cast<const uint4*>(&s_cc[8*kc]);
        z0 = fd(w.x, cc.x, z0); z1 = fd(w.y, cc.y, z1);
        z0 = fd(w.z, cc.z, z0); z1 = fd(w.w, cc.w, z1);
      }
#pragma unroll
      for (int q8 = 0; q8 < 8; ++q8) {
        int kc = (p0+2)*8 + q8;
        uint4 w  = s_wco[kc*256 + nn];
        uint4 cc = *reinterpret_cast<const uint4*>(&s_cc[8*kc]);
        z2 = fd(w.x, cc.x, z2); z3 = fd(w.y, cc.y, z3);
        z2 = fd(w.z, cc.z, z2); z3 = fd(w.w, cc.w, z3);
      }
      s_z[p0][nn]   = z0 + z1;
      s_z[p0+2][nn] = z2 + z3;
    }
    __syncthreads();

    if (t < 256) {
      float z = s_z[0][t] + s_z[1][t] + s_z[2][t] + s_z[3][t]
              + s_op[t] + s_bco[t];
      float o  = sigm(z);
      float hn = o * tanh_fast(s_cn[t]);
      out[(size_t)(ts+1)*(NB*HID) + b*HID + t] = hn;
      s_hh[t] = f2h_bits(hn);
    }
    __syncthreads();
  }
}

// ---------------- launch ----------------------------------------------------
extern "C" void kernel_launch(void* const* d_in, const int* in_sizes, int n_in,
                              void* d_out, int out_size, void* d_ws, size_t ws_size,
                              hipStream_t stream)
{
  const float* x   = (const float*)d_in[0];
  const float* Wx  = (const float*)d_in[1];
  const float* bx  = (const float*)d_in[2];
  const float* Wh  = (const float*)d_in[3];
  const float* bh  = (const float*)d_in[4];
  const float* Wci = (const float*)d_in[5];
  const float* bci = (const float*)d_in[6];
  const float* Wcf = (const float*)d_in[7];
  const float* bcf = (const float*)d_in[8];
  const float* Wco = (const float*)d_in[9];
  const float* bco = (const float*)d_in[10];
  float* out = (float*)d_out;
  uint4* ws4 = (uint4*)d_ws;
  u16* xw  = (u16*)((char*)d_ws + (size_t)W4_TOTAL*16);

  char* exb = (char*)d_ws + EXB_BYTE;          // overlay on WxT4 (PRE only)
  u16* gh  = (u16*)(exb + GH_BYTE);
  u16* gc  = (u16*)(exb + GC_BYTE);
  u32* bar = (u32*)(exb + BAR_BYTE);

  const size_t NEED = (size_t)W4_TOTAL*16 + (size_t)SEQ*NB*G4*2;  // ~129 MB
  const bool pre = (ws_size >= NEED);   // constant across calls -> capture-safe

  hipLaunchKernelGGL(prep_weights, dim3((W4_TOTAL + 255)/256), dim3(256), 0, stream,
                     Wh, Wci, Wcf, Wco, Wx, ws4);
  if (pre) {
    hipLaunchKernelGGL(bar_reset, dim3(1), dim3(1), 0, stream, bar);
    hipLaunchKernelGGL(xw_gemm, dim3(4096, 16), dim3(256), 0, stream,
                       x, Wx, bx, bh, xw);
    hipLaunchKernelGGL(lstm_scan_p, dim3(NBLK), dim3(512), 0, stream,
                       ws4, xw, bci, bcf, bco, out, gh, gc, bar);
  } else {
    hipLaunchKernelGGL(lstm_scan_np, dim3(32), dim3(512), 0, stream,
                       ws4, x, bx, bh, bci, bcf, bco, out);
  }
}

// Round 7
// 23461.086 us; speedup vs baseline: 1.0435x; 1.0435x over previous
//
#include <hip/hip_runtime.h>
#include <cstdint>
#include <cstddef>

// FC_LSTM on MI355X — Round 11: R10 resubmit (infra failure, no data).
// R9 evidence: weight-stationary sliced scan is CORRECT (absmax 0.0078125,
// same as R5) and compute is ~2-3K cyc/step, but 28K cyc/step total: both
// grid barriers used 32 atomic RMWs on ONE cache line -> ~400cyc serialized
// each -> ~13K cyc/barrier. FETCH 792MB = UC spin traffic on that line.
// Fix (R10, unbenched due to infra): sense barrier with PER-BLOCK arrival
// slots (256B apart, release epoch stores -> no RMW, no shared line),
// polled in parallel by 32 lanes (relaxed spin + paired acquire on exit).
// Data exchange unchanged (relaxed agent atomics, proven correct in R9).
// Audit found no deadlock/race: epochs monotone, poll is >=, reset is
// stream-ordered, 32 blocks co-resident. Projected ~8-9K cyc/step -> ~7ms.

typedef unsigned short u16;
typedef unsigned int   u32;
typedef unsigned long long u64;
typedef float  v4f __attribute__((ext_vector_type(4)));
typedef short  v8s __attribute__((ext_vector_type(8)));
typedef _Float16 h2 __attribute__((ext_vector_type(2)));

#define SEQ 2048
#define NB  32
#define HID 256
#define G4  1024
#define FIN 128
#define COFF (2049*NB*HID)   // element offset of memorys half of d_out

// uint4-unit offsets in ws
#define WH4_OFF  0        // [32][1024] : chunk kc (k=8kc..8kc+7), row n
#define WP4_OFF  32768    // [32][512]  : rows = [Wci n | Wcf n+256]
#define WCO4_OFF 49152    // [32][256]
#define WX4_OFF  57344    // [16][1024] (fallback path; overlay for PRE)
#define W4_TOTAL 73728    // uint4 count (1.125 MB)

// exchange overlay inside the WxT4 region (PRE path only; byte offsets)
#define EXB_BYTE  ((size_t)WX4_OFF * 16)
#define GH_BYTE   0          // u16[32][256]            (16 KB)
#define GC_BYTE   16384      // u16[2][32][256]         (32 KB)
#define ARR_BYTE  49152      // u32 arr[32*64] arrival slots (8 KB, 256B apart)

#define NBLK 32
#define NSL  8               // hidden slice per block

__device__ __forceinline__ u16 f2bf(float f) {
  u32 u = __builtin_bit_cast(u32, f);
  u32 r = (u + 0x7fffu + ((u >> 16) & 1u)) >> 16;
  return (u16)r;
}
__device__ __forceinline__ u16 f2h_bits(float f) {
  _Float16 h = (_Float16)f;
  return __builtin_bit_cast(u16, h);
}
__device__ __forceinline__ u32 pack2f(float a, float b) {
  u32 lo = f2h_bits(a);
  u32 hi = f2h_bits(b);
  return lo | (hi << 16);
}
__device__ __forceinline__ float fd(u32 w, u32 u, float acc) {
  h2 hw = __builtin_bit_cast(h2, w);
  h2 hu = __builtin_bit_cast(h2, u);
  return __builtin_amdgcn_fdot2(hw, hu, acc, false);
}
__device__ __forceinline__ float sigm(float v) { return 1.f / (1.f + __expf(-v)); }
__device__ __forceinline__ float tanh_fast(float x) {
  float xx = fminf(fmaxf(x, -15.f), 15.f);
  float e = __expf(2.f * xx);
  return (e - 1.f) / (e + 1.f);
}

// ---------------- Phase 0: weight repack (f32 -> f16 x8 chunks) -------------
__global__ __launch_bounds__(256) void prep_weights(
    const float* __restrict__ Wh, const float* __restrict__ Wci,
    const float* __restrict__ Wcf, const float* __restrict__ Wco,
    const float* __restrict__ Wx, uint4* __restrict__ ws4)
{
  int i = blockIdx.x * 256 + threadIdx.x;
  if (i >= W4_TOTAL) return;
  const float* src;
  if (i < WP4_OFF) {                       // WhT4
    int kc = i >> 10, n = i & 1023;
    src = Wh + n*256 + kc*8;
  } else if (i < WCO4_OFF) {               // WpT4
    int l = i - WP4_OFF; int kc = l >> 9, n = l & 511;
    src = ((n < 256) ? (Wci + n*256) : (Wcf + (n-256)*256)) + kc*8;
  } else if (i < WX4_OFF) {                // WcoT4
    int l = i - WCO4_OFF; int kc = l >> 8, n = l & 255;
    src = Wco + n*256 + kc*8;
  } else {                                 // WxT4 (fallback)
    int l = i - WX4_OFF; int kc = l >> 10, n = l & 1023;
    src = Wx + n*128 + kc*8;
  }
  uint4 r;
  r.x = pack2f(src[0], src[1]);
  r.y = pack2f(src[2], src[3]);
  r.z = pack2f(src[4], src[5]);
  r.w = pack2f(src[6], src[7]);
  ws4[i] = r;
}

// ---------------- arrival-slot reset (graph-replay safe) --------------------
__global__ __launch_bounds__(256) void bar_reset(u32* __restrict__ arr) {
  for (int i = threadIdx.x; i < NBLK*64; i += 256) arr[i] = 0u;
}

// ---------------- Phase 1: xw GEMM (bf16 MFMA, f32 inputs) ------------------
__global__ __launch_bounds__(256) void xw_gemm(
    const float* __restrict__ x, const float* __restrict__ Wx,
    const float* __restrict__ bx, const float* __restrict__ bh,
    u16* __restrict__ xw)
{
  int wave = threadIdx.x >> 6, lane = threadIdx.x & 63;
  int s = lane & 15, q = lane >> 4;
  int mtile = blockIdx.x;              // 0..4095
  int ntile = blockIdx.y * 4 + wave;   // 0..63
  const float* xa = x  + (size_t)(mtile*16 + s) * 128 + q*8;
  const float* wb = Wx + (size_t)(ntile*16 + s) * 128 + q*8;
  v4f acc = {0.f, 0.f, 0.f, 0.f};
#pragma unroll
  for (int ko = 0; ko < 4; ++ko) {
    float4 a0 = *reinterpret_cast<const float4*>(xa + ko*32);
    float4 a1 = *reinterpret_cast<const float4*>(xa + ko*32 + 4);
    float4 b0 = *reinterpret_cast<const float4*>(wb + ko*32);
    float4 b1 = *reinterpret_cast<const float4*>(wb + ko*32 + 4);
    v8s a, b;
    a[0]=(short)f2bf(a0.x); a[1]=(short)f2bf(a0.y); a[2]=(short)f2bf(a0.z); a[3]=(short)f2bf(a0.w);
    a[4]=(short)f2bf(a1.x); a[5]=(short)f2bf(a1.y); a[6]=(short)f2bf(a1.z); a[7]=(short)f2bf(a1.w);
    b[0]=(short)f2bf(b0.x); b[1]=(short)f2bf(b0.y); b[2]=(short)f2bf(b0.z); b[3]=(short)f2bf(b0.w);
    b[4]=(short)f2bf(b1.x); b[5]=(short)f2bf(b1.y); b[6]=(short)f2bf(b1.z); b[7]=(short)f2bf(b1.w);
    acc = __builtin_amdgcn_mfma_f32_16x16x32_bf16(a, b, acc, 0, 0, 0);
  }
  int n = ntile*16 + s;
  float bias = bx[n] + bh[n];
#pragma unroll
  for (int p = 0; p < 4; ++p) {
    int m = mtile*16 + q*4 + p;
    int bb = m >> 11, t = m & 2047;   // r = b*2048 + t
    xw[(size_t)(t*NB + bb) * G4 + n] = f2h_bits(acc[p] + bias);
  }
}

// ---------------- contention-free grid barrier ------------------------------
// Arrival: block bid release-stores monotone epoch to its OWN 256B-spaced
// slot (no RMW, no shared line). Wait: 32 lanes poll the 32 slots in
// parallel (relaxed spin, s_sleep backoff), then one paired acquire load
// per slot to order subsequent reads.
__device__ __forceinline__ void gbar2(u32* arr, int bid, u32 ep) {
  __syncthreads();   // all of this block's exchange stores drained
  if (threadIdx.x == 0)
    __hip_atomic_store(&arr[bid*64], ep, __ATOMIC_RELEASE, __HIP_MEMORY_SCOPE_AGENT);
  if (threadIdx.x < NBLK) {
    u32* slot = &arr[threadIdx.x*64];
    while (__hip_atomic_load(slot, __ATOMIC_RELAXED, __HIP_MEMORY_SCOPE_AGENT) < ep)
      __builtin_amdgcn_s_sleep(4);
    (void)__hip_atomic_load(slot, __ATOMIC_ACQUIRE, __HIP_MEMORY_SCOPE_AGENT);
  }
  __syncthreads();
}

// ---------------- Phase 2 (PRE): weight-stationary sliced scan --------------
// 32 blocks; block k owns n in [8k, 8k+8) for ALL 32 batches.
// 512 threads: role = tid>>8 (0: i,f + c_new | 1: o-part,g + z + h_new);
// p = tid&255 -> b = p>>3, j = p&7, n = 8*blockIdx.x + j.
__global__ __launch_bounds__(512) void lstm_scan_p(
    const uint4* __restrict__ ws4, const u16* __restrict__ xw,
    const float* __restrict__ bci, const float* __restrict__ bcf,
    const float* __restrict__ bco, float* __restrict__ out,
    u16* __restrict__ gh, u16* __restrict__ gc, u32* __restrict__ arr)
{
  const int tid  = threadIdx.x;
  const int bid  = blockIdx.x;
  const int nb   = bid * NSL;
  const int role = tid >> 8;
  const int p    = tid & 255;
  const int b    = p >> 3;
  const int j    = p & 7;
  const int n    = nb + j;

  // weights: [7 types][8 j][33 pitch] uint4 (pad 32->33 kills bank conflicts)
  __shared__ __align__(16) uint4 s_w4[7*8*33];
  __shared__ __align__(16) u16 s_h16[32*264];   // h, pitch 264 u16 (=33 uint4)
  __shared__ __align__(16) u16 s_cA[32*264];    // c ping
  __shared__ __align__(16) u16 s_cB[32*264];    // c pong (zeroed: c_{-1}=0)
  __shared__ float s_i[256], s_f[256], s_g[256], s_op[256], s_cnf[256], s_cst[256];
  __shared__ float s_bci[NSL], s_bcf[NSL], s_bco[NSL];

  const uint4* WhT4  = ws4 + WH4_OFF;
  const uint4* WpT4  = ws4 + WP4_OFF;
  const uint4* WcoT4 = ws4 + WCO4_OFF;

  // ---- load slice weights to LDS (once) ----
  for (int idx = tid; idx < 7*8*32; idx += 512) {
    int type = idx >> 8;          // 0..6
    int jj   = (idx >> 5) & 7;
    int kc   = idx & 31;
    int row  = nb + jj;
    uint4 v;
    if      (type == 0) v = WhT4[kc*1024 + row];         // Wh_i
    else if (type == 1) v = WhT4[kc*1024 + 256 + row];   // Wh_f
    else if (type == 2) v = WpT4[kc*512 + row];          // Wci
    else if (type == 3) v = WpT4[kc*512 + 256 + row];    // Wcf
    else if (type == 4) v = WhT4[kc*1024 + 512 + row];   // Wh_o
    else if (type == 5) v = WhT4[kc*1024 + 768 + row];   // Wh_g
    else                v = WcoT4[kc*256 + row];         // Wco
    s_w4[type*264 + jj*33 + kc] = v;
  }
  if (tid < NSL) {
    s_bci[tid] = bci[nb + tid];
    s_bcf[tid] = bcf[nb + tid];
    s_bco[tid] = bco[nb + tid];
  }
  for (int q = tid; q < 32*264; q += 512) s_cB[q] = 0;   // c_old for step 0
  if (role == 0) {
    s_cst[p] = 0.f;
    __hip_atomic_store(&gh[b*256 + n], (u16)0, __ATOMIC_RELAXED, __HIP_MEMORY_SCOPE_AGENT);
    out[b*HID + n] = 0.f;          // h0
    out[COFF + b*HID + n] = 0.f;   // c0
  }
  gbar2(arr, bid, 1);   // init barrier: all zeros visible

  const uint4* h4 = (const uint4*)s_h16;
  int csw = 0;

  for (int ts = 0; ts < SEQ; ++ts) {
    u16* c_old16 = csw ? s_cA : s_cB;   // full c_{ts-1} (f16)
    u16* c_new16 = csw ? s_cB : s_cA;   // filled with c_ts after barrier 1
    const uint4* co4 = (const uint4*)c_old16;

    // xw prefetch (cols per R5 role mapping: i/f for role0, o/g for role1)
    const u16* xr = xw + ((size_t)ts*NB + b) * G4;
    u16 xwa = xr[role == 0 ? n       : 512 + n];
    u16 xwb = xr[role == 0 ? 256 + n : 768 + n];

    // (A) gh -> s_h16 (relaxed agent loads: cross-XCD safe, proven in R9)
    for (int q = tid; q < 2048; q += 512) {
      int bb = q >> 6, k64 = q & 63;   // 64 u64 per 256-u16 row
      u64 v = __hip_atomic_load((u64*)gh + q, __ATOMIC_RELAXED, __HIP_MEMORY_SCOPE_AGENT);
      ((u64*)s_h16)[bb*66 + k64] = v;
    }
    __syncthreads();

    // (B) gate dots — R5 order: Wh kc0..31 (x,z->a0; y,w->a1), then
    //     peephole kc0..31 continuing a0,a1 (role0 only); acc=a0+a1; +=xw.
    const uint4* wA = s_w4 + (role ? 4*264 : 0*264) + j*33;   // Wh_i / Wh_o
    float a0 = 0.f, a1 = 0.f;
#pragma unroll 8
    for (int kc = 0; kc < 32; ++kc) {
      uint4 w  = wA[kc];
      uint4 hh = h4[b*33 + kc];
      a0 = fd(w.x, hh.x, a0); a1 = fd(w.y, hh.y, a1);
      a0 = fd(w.z, hh.z, a0); a1 = fd(w.w, hh.w, a1);
    }
    if (role == 0) {
      const uint4* wP = s_w4 + 2*264 + j*33;                  // Wci
#pragma unroll 8
      for (int kc = 0; kc < 32; ++kc) {
        uint4 w  = wP[kc];
        uint4 cc = co4[b*33 + kc];
        a0 = fd(w.x, cc.x, a0); a1 = fd(w.y, cc.y, a1);
        a0 = fd(w.z, cc.z, a0); a1 = fd(w.w, cc.w, a1);
      }
    }
    float accA = a0 + a1;
    accA += (float)__builtin_bit_cast(_Float16, xwa);

    const uint4* wB = s_w4 + (role ? 5*264 : 1*264) + j*33;   // Wh_f / Wh_g
    float b0 = 0.f, b1 = 0.f;
#pragma unroll 8
    for (int kc = 0; kc < 32; ++kc) {
      uint4 w  = wB[kc];
      uint4 hh = h4[b*33 + kc];
      b0 = fd(w.x, hh.x, b0); b1 = fd(w.y, hh.y, b1);
      b0 = fd(w.z, hh.z, b0); b1 = fd(w.w, hh.w, b1);
    }
    if (role == 0) {
      const uint4* wP = s_w4 + 3*264 + j*33;                  // Wcf
#pragma unroll 8
      for (int kc = 0; kc < 32; ++kc) {
        uint4 w  = wP[kc];
        uint4 cc = co4[b*33 + kc];
        b0 = fd(w.x, cc.x, b0); b1 = fd(w.y, cc.y, b1);
        b0 = fd(w.z, cc.z, b0); b1 = fd(w.w, cc.w, b1);
      }
    }
    float accB = b0 + b1;
    accB += (float)__builtin_bit_cast(_Float16, xwb);

    if (role == 0) {
      s_i[p] = sigm(accA + s_bci[j]);
      s_f[p] = sigm(accB + s_bcf[j]);
    } else {
      s_op[p] = accA;               // o pre-activation (bias+peephole later)
      s_g[p]  = tanh_fast(accB);
    }
    __syncthreads();

    // (C) c_new (role0), publish f16 slice
    if (role == 0) {
      float cn = s_f[p]*s_cst[p] + s_i[p]*s_g[p];
      s_cst[p] = cn;
      s_cnf[p] = cn;
      u16 cb = f2h_bits(cn);
      __hip_atomic_store(&gc[(size_t)(ts & 1)*8192 + b*256 + n], cb,
                         __ATOMIC_RELAXED, __HIP_MEMORY_SCOPE_AGENT);
      out[COFF + (size_t)(ts+1)*(NB*HID) + b*HID + n] = cn;
    }
    gbar2(arr, bid, (u32)(2*ts + 2));

    // (D) gc[ts&1] -> c_new16 (full c_ts; also next step's c_old)
    {
      const u64* gsrc = (const u64*)(gc + (size_t)(ts & 1)*8192);
      for (int q = tid; q < 2048; q += 512) {
        int bb = q >> 6, k64 = q & 63;
        u64 v = __hip_atomic_load((u64*)gsrc + q, __ATOMIC_RELAXED, __HIP_MEMORY_SCOPE_AGENT);
        ((u64*)c_new16)[bb*66 + k64] = v;
      }
    }
    __syncthreads();

    // (E) o-peephole + h_new (role1). z-part order replicates R5 exactly.
    if (role == 1) {
      const uint4* wz  = s_w4 + 6*264 + j*33;                 // Wco
      const uint4* cn4 = (const uint4*)c_new16;
      float zacc[4];
#pragma unroll
      for (int p4 = 0; p4 < 4; ++p4) {
        float z0 = 0.f, z1 = 0.f;
#pragma unroll
        for (int q8 = 0; q8 < 8; ++q8) {
          int kc = p4*8 + q8;
          uint4 w  = wz[kc];
          uint4 cc = cn4[b*33 + kc];
          z0 = fd(w.x, cc.x, z0); z1 = fd(w.y, cc.y, z1);
          z0 = fd(w.z, cc.z, z0); z1 = fd(w.w, cc.w, z1);
        }
        zacc[p4] = z0 + z1;
      }
      float z = zacc[0] + zacc[1] + zacc[2] + zacc[3] + s_op[p] + s_bco[j];
      float o  = sigm(z);
      float hn = o * tanh_fast(s_cnf[p]);
      out[(size_t)(ts+1)*(NB*HID) + b*HID + n] = hn;
      __hip_atomic_store(&gh[b*256 + n], f2h_bits(hn),
                         __ATOMIC_RELAXED, __HIP_MEMORY_SCOPE_AGENT);
    }
    gbar2(arr, bid, (u32)(2*ts + 3));

    csw ^= 1;
  }
}

// ---------------- fallback (non-PRE) scan: R5 per-batch kernel --------------
__global__ __launch_bounds__(512, 2) void lstm_scan_np(
    const uint4* __restrict__ ws4, const float* __restrict__ x,
    const float* __restrict__ bx, const float* __restrict__ bh,
    const float* __restrict__ bci, const float* __restrict__ bcf,
    const float* __restrict__ bco, float* __restrict__ out)
{
  const int b = blockIdx.x, t = threadIdx.x;
  const uint4* WhT4  = ws4 + WH4_OFF;
  const uint4* WpT4  = ws4 + WP4_OFF;
  const uint4* WcoT4 = ws4 + WCO4_OFF;
  const uint4* WxT4  = ws4 + WX4_OFF;

  __shared__ __align__(16) uint4 s_wco[8192];
  __shared__ __align__(16) float s_i[256], s_f[256], s_g[256], s_op[256];
  __shared__ __align__(16) float s_c[256], s_cn[256], s_z[4][256];
  __shared__ __align__(16) u16 s_hh[256], s_cc[256], s_x[128];
  __shared__ float s_bci[256], s_bcf[256], s_bco[256];

  for (int i = t; i < 8192; i += 512) s_wco[i] = WcoT4[i];
  if (t < 256) {
    s_c[t] = 0.f; s_hh[t] = 0; s_cc[t] = 0;
    s_bci[t] = bci[t]; s_bcf[t] = bcf[t]; s_bco[t] = bco[t];
    out[b*HID + t] = 0.f;
    out[COFF + b*HID + t] = 0.f;
  }
  const int n1 = 512 + t;
  float biasA = bx[t] + bh[t], biasB = bx[n1] + bh[n1];
  __syncthreads();

  for (int ts = 0; ts < SEQ; ++ts) {
    if (t < 128) {
      const float* xr2 = x + (size_t)(b*SEQ + ts) * FIN;
      s_x[t] = f2h_bits(xr2[t]);
    }
    __syncthreads();

    float a0 = 0.f, a1 = 0.f, c0 = 0.f, c1 = 0.f;
#pragma unroll 4
    for (int kc = 0; kc < 32; ++kc) {
      uint4 wA = WhT4[kc*1024 + t];
      uint4 wB = WhT4[kc*1024 + n1];
      uint4 hh = *reinterpret_cast<const uint4*>(&s_hh[8*kc]);
      a0 = fd(wA.x, hh.x, a0); a1 = fd(wA.y, hh.y, a1);
      a0 = fd(wA.z, hh.z, a0); a1 = fd(wA.w, hh.w, a1);
      c0 = fd(wB.x, hh.x, c0); c1 = fd(wB.y, hh.y, c1);
      c0 = fd(wB.z, hh.z, c0); c1 = fd(wB.w, hh.w, c1);
    }
#pragma unroll 4
    for (int kc = 0; kc < 16; ++kc) {
      uint4 wA = WxT4[kc*1024 + t];
      uint4 wB = WxT4[kc*1024 + n1];
      uint4 xx = *reinterpret_cast<const uint4*>(&s_x[8*kc]);
      a0 = fd(wA.x, xx.x, a0); a1 = fd(wA.y, xx.y, a1);
      a0 = fd(wA.z, xx.z, a0); a1 = fd(wA.w, xx.w, a1);
      c0 = fd(wB.x, xx.x, c0); c1 = fd(wB.y, xx.y, c1);
      c0 = fd(wB.z, xx.z, c0); c1 = fd(wB.w, xx.w, c1);
    }
#pragma unroll 4
    for (int kc = 0; kc < 32; ++kc) {
      uint4 w  = WpT4[kc*512 + t];
      uint4 cc = *reinterpret_cast<const uint4*>(&s_cc[8*kc]);
      a0 = fd(w.x, cc.x, a0); a1 = fd(w.y, cc.y, a1);
      a0 = fd(w.z, cc.z, a0); a1 = fd(w.w, cc.w, a1);
    }
    float accA = a0 + a1 + biasA;
    float accB = c0 + c1 + biasB;

    int idx = t & 255;
    if (t < 256) { s_i[idx]  = sigm(accA + s_bci[idx]); s_op[idx] = accB; }
    else         { s_f[idx]  = sigm(accA + s_bcf[idx]); s_g[idx]  = tanh_fast(accB); }
    __syncthreads();

    if (t < 256) {
      float cn = s_f[t]*s_c[t] + s_i[t]*s_g[t];
      s_cn[t] = cn; s_c[t] = cn;
      s_cc[t] = f2h_bits(cn);
      out[COFF + (size_t)(ts+1)*(NB*HID) + b*HID + t] = cn;
    }
    __syncthreads();

    {
      int nn = t & 255, p0 = t >> 8;
      float z0 = 0.f, z1 = 0.f, z2 = 0.f, z3 = 0.f;
#pragma unroll
      for (int q8 = 0; q8 < 8; ++q8) {
        int kc = p0*8 + q8;
        uint4 w  = s_wco[kc*256 + nn];
        uint4 cc = *reinterpret_cast<const uint4*>(&s_cc[8*kc]);
        z0 = fd(w.x, cc.x, z0); z1 = fd(w.y, cc.y, z1);
        z0 = fd(w.z, cc.z, z0); z1 = fd(w.w, cc.w, z1);
      }
#pragma unroll
      for (int q8 = 0; q8 < 8; ++q8) {
        int kc = (p0+2)*8 + q8;
        uint4 w  = s_wco[kc*256 + nn];
        uint4 cc = *reinterpret_cast<const uint4*>(&s_cc[8*kc]);
        z2 = fd(w.x, cc.x, z2); z3 = fd(w.y, cc.y, z3);
        z2 = fd(w.z, cc.z, z2); z3 = fd(w.w, cc.w, z3);
      }
      s_z[p0][nn]   = z0 + z1;
      s_z[p0+2][nn] = z2 + z3;
    }
    __syncthreads();

    if (t < 256) {
      float z = s_z[0][t] + s_z[1][t] + s_z[2][t] + s_z[3][t]
              + s_op[t] + s_bco[t];
      float o  = sigm(z);
      float hn = o * tanh_fast(s_cn[t]);
      out[(size_t)(ts+1)*(NB*HID) + b*HID + t] = hn;
      s_hh[t] = f2h_bits(hn);
    }
    __syncthreads();
  }
}

// ---------------- launch ----------------------------------------------------
extern "C" void kernel_launch(void* const* d_in, const int* in_sizes, int n_in,
                              void* d_out, int out_size, void* d_ws, size_t ws_size,
                              hipStream_t stream)
{
  const float* x   = (const float*)d_in[0];
  const float* Wx  = (const float*)d_in[1];
  const float* bx  = (const float*)d_in[2];
  const float* Wh  = (const float*)d_in[3];
  const float* bh  = (const float*)d_in[4];
  const float* Wci = (const float*)d_in[5];
  const float* bci = (const float*)d_in[6];
  const float* Wcf = (const float*)d_in[7];
  const float* bcf = (const float*)d_in[8];
  const float* Wco = (const float*)d_in[9];
  const float* bco = (const float*)d_in[10];
  float* out = (float*)d_out;
  uint4* ws4 = (uint4*)d_ws;
  u16* xw  = (u16*)((char*)d_ws + (size_t)W4_TOTAL*16);

  char* exb = (char*)d_ws + EXB_BYTE;          // overlay on WxT4 (PRE only)
  u16* gh  = (u16*)(exb + GH_BYTE);
  u16* gc  = (u16*)(exb + GC_BYTE);
  u32* arr = (u32*)(exb + ARR_BYTE);

  const size_t NEED = (size_t)W4_TOTAL*16 + (size_t)SEQ*NB*G4*2;  // ~129 MB
  const bool pre = (ws_size >= NEED);   // constant across calls -> capture-safe

  hipLaunchKernelGGL(prep_weights, dim3((W4_TOTAL + 255)/256), dim3(256), 0, stream,
                     Wh, Wci, Wcf, Wco, Wx, ws4);
  if (pre) {
    hipLaunchKernelGGL(bar_reset, dim3(1), dim3(256), 0, stream, arr);
    hipLaunchKernelGGL(xw_gemm, dim3(4096, 16), dim3(256), 0, stream,
                       x, Wx, bx, bh, xw);
    hipLaunchKernelGGL(lstm_scan_p, dim3(NBLK), dim3(512), 0, stream,
                       ws4, xw, bci, bcf, bco, out, gh, gc, arr);
  } else {
    hipLaunchKernelGGL(lstm_scan_np, dim3(32), dim3(512), 0, stream,
                       ws4, x, bx, bh, bci, bcf, bco, out);
  }
}

// Round 8
// 17226.526 us; speedup vs baseline: 1.4211x; 1.3619x over previous
//
#include <hip/hip_runtime.h>
#include <cstdint>
#include <cstddef>

// FC_LSTM on MI355X — Round 12: fence-free grid sync (kill buffer_wbl2/inv).
// R9/R11 evidence: weight-stationary sliced scan is bit-correct and compute
// is ~2.5K cyc/step, but BOTH barrier designs cost ~24K cyc/step. Root
// cause: agent-scope RELEASE/ACQUIRE on gfx94x+ compile to buffer_wbl2 /
// buffer_inv — FULL per-XCD L2 writeback/invalidate, 4096 times. FETCH
// 853MB = post-inv L2 refetch.
// Fix: all cross-block data already moves via RELAXED agent atomics (sc1,
// UC at the coherence point; proven coherent by R9/R11 bit-exactness).
// Ordering data-before-flag: __syncthreads drains vmcnt(0) in every wave
// (stores acked) before the flag store; consumer's poll control-dependency
// orders its UC data loads. -> barrier with ZERO L2 flushes.
// Projected: ~8-10K cyc/step -> scan ~7-9ms.

typedef unsigned short u16;
typedef unsigned int   u32;
typedef unsigned long long u64;
typedef float  v4f __attribute__((ext_vector_type(4)));
typedef short  v8s __attribute__((ext_vector_type(8)));
typedef _Float16 h2 __attribute__((ext_vector_type(2)));

#define SEQ 2048
#define NB  32
#define HID 256
#define G4  1024
#define FIN 128
#define COFF (2049*NB*HID)   // element offset of memorys half of d_out

// uint4-unit offsets in ws
#define WH4_OFF  0        // [32][1024] : chunk kc (k=8kc..8kc+7), row n
#define WP4_OFF  32768    // [32][512]  : rows = [Wci n | Wcf n+256]
#define WCO4_OFF 49152    // [32][256]
#define WX4_OFF  57344    // [16][1024] (fallback path; overlay for PRE)
#define W4_TOTAL 73728    // uint4 count (1.125 MB)

// exchange overlay inside the WxT4 region (PRE path only; byte offsets)
#define EXB_BYTE  ((size_t)WX4_OFF * 16)
#define GH_BYTE   0          // u16[32][256]            (16 KB)
#define GC_BYTE   16384      // u16[2][32][256]         (32 KB)
#define ARR_BYTE  49152      // u32 arr[32*64] arrival slots (8 KB, 256B apart)

#define NBLK 32
#define NSL  8               // hidden slice per block

__device__ __forceinline__ u16 f2bf(float f) {
  u32 u = __builtin_bit_cast(u32, f);
  u32 r = (u + 0x7fffu + ((u >> 16) & 1u)) >> 16;
  return (u16)r;
}
__device__ __forceinline__ u16 f2h_bits(float f) {
  _Float16 h = (_Float16)f;
  return __builtin_bit_cast(u16, h);
}
__device__ __forceinline__ u32 pack2f(float a, float b) {
  u32 lo = f2h_bits(a);
  u32 hi = f2h_bits(b);
  return lo | (hi << 16);
}
__device__ __forceinline__ float fd(u32 w, u32 u, float acc) {
  h2 hw = __builtin_bit_cast(h2, w);
  h2 hu = __builtin_bit_cast(h2, u);
  return __builtin_amdgcn_fdot2(hw, hu, acc, false);
}
__device__ __forceinline__ float sigm(float v) { return 1.f / (1.f + __expf(-v)); }
__device__ __forceinline__ float tanh_fast(float x) {
  float xx = fminf(fmaxf(x, -15.f), 15.f);
  float e = __expf(2.f * xx);
  return (e - 1.f) / (e + 1.f);
}

// ---------------- Phase 0: weight repack (f32 -> f16 x8 chunks) -------------
__global__ __launch_bounds__(256) void prep_weights(
    const float* __restrict__ Wh, const float* __restrict__ Wci,
    const float* __restrict__ Wcf, const float* __restrict__ Wco,
    const float* __restrict__ Wx, uint4* __restrict__ ws4)
{
  int i = blockIdx.x * 256 + threadIdx.x;
  if (i >= W4_TOTAL) return;
  const float* src;
  if (i < WP4_OFF) {                       // WhT4
    int kc = i >> 10, n = i & 1023;
    src = Wh + n*256 + kc*8;
  } else if (i < WCO4_OFF) {               // WpT4
    int l = i - WP4_OFF; int kc = l >> 9, n = l & 511;
    src = ((n < 256) ? (Wci + n*256) : (Wcf + (n-256)*256)) + kc*8;
  } else if (i < WX4_OFF) {                // WcoT4
    int l = i - WCO4_OFF; int kc = l >> 8, n = l & 255;
    src = Wco + n*256 + kc*8;
  } else {                                 // WxT4 (fallback)
    int l = i - WX4_OFF; int kc = l >> 10, n = l & 1023;
    src = Wx + n*128 + kc*8;
  }
  uint4 r;
  r.x = pack2f(src[0], src[1]);
  r.y = pack2f(src[2], src[3]);
  r.z = pack2f(src[4], src[5]);
  r.w = pack2f(src[6], src[7]);
  ws4[i] = r;
}

// ---------------- arrival-slot reset (graph-replay safe) --------------------
__global__ __launch_bounds__(256) void bar_reset(u32* __restrict__ arr) {
  for (int i = threadIdx.x; i < NBLK*64; i += 256) arr[i] = 0u;
}

// ---------------- Phase 1: xw GEMM (bf16 MFMA, f32 inputs) ------------------
__global__ __launch_bounds__(256) void xw_gemm(
    const float* __restrict__ x, const float* __restrict__ Wx,
    const float* __restrict__ bx, const float* __restrict__ bh,
    u16* __restrict__ xw)
{
  int wave = threadIdx.x >> 6, lane = threadIdx.x & 63;
  int s = lane & 15, q = lane >> 4;
  int mtile = blockIdx.x;              // 0..4095
  int ntile = blockIdx.y * 4 + wave;   // 0..63
  const float* xa = x  + (size_t)(mtile*16 + s) * 128 + q*8;
  const float* wb = Wx + (size_t)(ntile*16 + s) * 128 + q*8;
  v4f acc = {0.f, 0.f, 0.f, 0.f};
#pragma unroll
  for (int ko = 0; ko < 4; ++ko) {
    float4 a0 = *reinterpret_cast<const float4*>(xa + ko*32);
    float4 a1 = *reinterpret_cast<const float4*>(xa + ko*32 + 4);
    float4 b0 = *reinterpret_cast<const float4*>(wb + ko*32);
    float4 b1 = *reinterpret_cast<const float4*>(wb + ko*32 + 4);
    v8s a, b;
    a[0]=(short)f2bf(a0.x); a[1]=(short)f2bf(a0.y); a[2]=(short)f2bf(a0.z); a[3]=(short)f2bf(a0.w);
    a[4]=(short)f2bf(a1.x); a[5]=(short)f2bf(a1.y); a[6]=(short)f2bf(a1.z); a[7]=(short)f2bf(a1.w);
    b[0]=(short)f2bf(b0.x); b[1]=(short)f2bf(b0.y); b[2]=(short)f2bf(b0.z); b[3]=(short)f2bf(b0.w);
    b[4]=(short)f2bf(b1.x); b[5]=(short)f2bf(b1.y); b[6]=(short)f2bf(b1.z); b[7]=(short)f2bf(b1.w);
    acc = __builtin_amdgcn_mfma_f32_16x16x32_bf16(a, b, acc, 0, 0, 0);
  }
  int n = ntile*16 + s;
  float bias = bx[n] + bh[n];
#pragma unroll
  for (int p = 0; p < 4; ++p) {
    int m = mtile*16 + q*4 + p;
    int bb = m >> 11, t = m & 2047;   // r = b*2048 + t
    xw[(size_t)(t*NB + bb) * G4 + n] = f2h_bits(acc[p] + bias);
  }
}

// ---------------- fence-free grid barrier -----------------------------------
// All cross-block data moves via RELAXED agent-scope atomics (sc1/UC at the
// coherence point). __syncthreads() drains vmcnt(0) in EVERY wave, so all of
// this block's UC data stores are acked at the coherence point before thread
// 0 stores the (relaxed) flag. The consumer's poll control-dependency orders
// its subsequent UC data loads. No release/acquire -> no buffer_wbl2 /
// buffer_inv (the full-L2 flush pair that cost ~24K cyc/step in R9/R11).
__device__ __forceinline__ void gbar3(u32* arr, int bid, u32 ep) {
  __syncthreads();   // compiler+hw barrier; drains vmcnt(0) per wave
  asm volatile("" ::: "memory");
  if (threadIdx.x == 0)
    __hip_atomic_store(&arr[bid*64], ep, __ATOMIC_RELAXED, __HIP_MEMORY_SCOPE_AGENT);
  if (threadIdx.x < NBLK) {
    u32* slot = &arr[threadIdx.x*64];
    while (__hip_atomic_load(slot, __ATOMIC_RELAXED, __HIP_MEMORY_SCOPE_AGENT) < ep)
      __builtin_amdgcn_s_sleep(1);
  }
  asm volatile("" ::: "memory");
  __syncthreads();
}

// ---------------- Phase 2 (PRE): weight-stationary sliced scan --------------
// 32 blocks; block k owns n in [8k, 8k+8) for ALL 32 batches.
// 512 threads: role = tid>>8 (0: i,f + c_new | 1: o-part,g + z + h_new);
// p = tid&255 -> b = p>>3, j = p&7, n = 8*blockIdx.x + j.
__global__ __launch_bounds__(512) void lstm_scan_p(
    const uint4* __restrict__ ws4, const u16* __restrict__ xw,
    const float* __restrict__ bci, const float* __restrict__ bcf,
    const float* __restrict__ bco, float* __restrict__ out,
    u16* __restrict__ gh, u16* __restrict__ gc, u32* __restrict__ arr)
{
  const int tid  = threadIdx.x;
  const int bid  = blockIdx.x;
  const int nb   = bid * NSL;
  const int role = tid >> 8;
  const int p    = tid & 255;
  const int b    = p >> 3;
  const int j    = p & 7;
  const int n    = nb + j;

  // weights: [7 types][8 j][33 pitch] uint4 (pad 32->33 kills bank conflicts)
  __shared__ __align__(16) uint4 s_w4[7*8*33];
  __shared__ __align__(16) u16 s_h16[32*264];   // h, pitch 264 u16 (=33 uint4)
  __shared__ __align__(16) u16 s_cA[32*264];    // c ping
  __shared__ __align__(16) u16 s_cB[32*264];    // c pong (zeroed: c_{-1}=0)
  __shared__ float s_i[256], s_f[256], s_g[256], s_op[256], s_cnf[256], s_cst[256];
  __shared__ float s_bci[NSL], s_bcf[NSL], s_bco[NSL];

  const uint4* WhT4  = ws4 + WH4_OFF;
  const uint4* WpT4  = ws4 + WP4_OFF;
  const uint4* WcoT4 = ws4 + WCO4_OFF;

  // ---- load slice weights to LDS (once) ----
  for (int idx = tid; idx < 7*8*32; idx += 512) {
    int type = idx >> 8;          // 0..6
    int jj   = (idx >> 5) & 7;
    int kc   = idx & 31;
    int row  = nb + jj;
    uint4 v;
    if      (type == 0) v = WhT4[kc*1024 + row];         // Wh_i
    else if (type == 1) v = WhT4[kc*1024 + 256 + row];   // Wh_f
    else if (type == 2) v = WpT4[kc*512 + row];          // Wci
    else if (type == 3) v = WpT4[kc*512 + 256 + row];    // Wcf
    else if (type == 4) v = WhT4[kc*1024 + 512 + row];   // Wh_o
    else if (type == 5) v = WhT4[kc*1024 + 768 + row];   // Wh_g
    else                v = WcoT4[kc*256 + row];         // Wco
    s_w4[type*264 + jj*33 + kc] = v;
  }
  if (tid < NSL) {
    s_bci[tid] = bci[nb + tid];
    s_bcf[tid] = bcf[nb + tid];
    s_bco[tid] = bco[nb + tid];
  }
  for (int q = tid; q < 32*264; q += 512) s_cB[q] = 0;   // c_old for step 0
  if (role == 0) {
    s_cst[p] = 0.f;
    __hip_atomic_store(&gh[b*256 + n], (u16)0, __ATOMIC_RELAXED, __HIP_MEMORY_SCOPE_AGENT);
    out[b*HID + n] = 0.f;          // h0
    out[COFF + b*HID + n] = 0.f;   // c0
  }
  gbar3(arr, bid, 1);   // init barrier: all zeros visible

  const uint4* h4 = (const uint4*)s_h16;
  int csw = 0;

  for (int ts = 0; ts < SEQ; ++ts) {
    u16* c_old16 = csw ? s_cA : s_cB;   // full c_{ts-1} (f16)
    u16* c_new16 = csw ? s_cB : s_cA;   // filled with c_ts after barrier 1
    const uint4* co4 = (const uint4*)c_old16;

    // xw prefetch (cols per R5 role mapping: i/f for role0, o/g for role1)
    const u16* xr = xw + ((size_t)ts*NB + b) * G4;
    u16 xwa = xr[role == 0 ? n       : 512 + n];
    u16 xwb = xr[role == 0 ? 256 + n : 768 + n];

    // (A) gh -> s_h16 (relaxed agent UC loads: cross-XCD coherent, R9-proven)
    for (int q = tid; q < 2048; q += 512) {
      int bb = q >> 6, k64 = q & 63;   // 64 u64 per 256-u16 row
      u64 v = __hip_atomic_load((u64*)gh + q, __ATOMIC_RELAXED, __HIP_MEMORY_SCOPE_AGENT);
      ((u64*)s_h16)[bb*66 + k64] = v;
    }
    __syncthreads();

    // (B) gate dots — R5 order: Wh kc0..31 (x,z->a0; y,w->a1), then
    //     peephole kc0..31 continuing a0,a1 (role0 only); acc=a0+a1; +=xw.
    const uint4* wA = s_w4 + (role ? 4*264 : 0*264) + j*33;   // Wh_i / Wh_o
    float a0 = 0.f, a1 = 0.f;
#pragma unroll 8
    for (int kc = 0; kc < 32; ++kc) {
      uint4 w  = wA[kc];
      uint4 hh = h4[b*33 + kc];
      a0 = fd(w.x, hh.x, a0); a1 = fd(w.y, hh.y, a1);
      a0 = fd(w.z, hh.z, a0); a1 = fd(w.w, hh.w, a1);
    }
    if (role == 0) {
      const uint4* wP = s_w4 + 2*264 + j*33;                  // Wci
#pragma unroll 8
      for (int kc = 0; kc < 32; ++kc) {
        uint4 w  = wP[kc];
        uint4 cc = co4[b*33 + kc];
        a0 = fd(w.x, cc.x, a0); a1 = fd(w.y, cc.y, a1);
        a0 = fd(w.z, cc.z, a0); a1 = fd(w.w, cc.w, a1);
      }
    }
    float accA = a0 + a1;
    accA += (float)__builtin_bit_cast(_Float16, xwa);

    const uint4* wB = s_w4 + (role ? 5*264 : 1*264) + j*33;   // Wh_f / Wh_g
    float b0 = 0.f, b1 = 0.f;
#pragma unroll 8
    for (int kc = 0; kc < 32; ++kc) {
      uint4 w  = wB[kc];
      uint4 hh = h4[b*33 + kc];
      b0 = fd(w.x, hh.x, b0); b1 = fd(w.y, hh.y, b1);
      b0 = fd(w.z, hh.z, b0); b1 = fd(w.w, hh.w, b1);
    }
    if (role == 0) {
      const uint4* wP = s_w4 + 3*264 + j*33;                  // Wcf
#pragma unroll 8
      for (int kc = 0; kc < 32; ++kc) {
        uint4 w  = wP[kc];
        uint4 cc = co4[b*33 + kc];
        b0 = fd(w.x, cc.x, b0); b1 = fd(w.y, cc.y, b1);
        b0 = fd(w.z, cc.z, b0); b1 = fd(w.w, cc.w, b1);
      }
    }
    float accB = b0 + b1;
    accB += (float)__builtin_bit_cast(_Float16, xwb);

    if (role == 0) {
      s_i[p] = sigm(accA + s_bci[j]);
      s_f[p] = sigm(accB + s_bcf[j]);
    } else {
      s_op[p] = accA;               // o pre-activation (bias+peephole later)
      s_g[p]  = tanh_fast(accB);
    }
    __syncthreads();

    // (C) c_new (role0), publish f16 slice (relaxed UC store)
    if (role == 0) {
      float cn = s_f[p]*s_cst[p] + s_i[p]*s_g[p];
      s_cst[p] = cn;
      s_cnf[p] = cn;
      u16 cb = f2h_bits(cn);
      __hip_atomic_store(&gc[(size_t)(ts & 1)*8192 + b*256 + n], cb,
                         __ATOMIC_RELAXED, __HIP_MEMORY_SCOPE_AGENT);
      out[COFF + (size_t)(ts+1)*(NB*HID) + b*HID + n] = cn;
    }
    gbar3(arr, bid, (u32)(2*ts + 2));

    // (D) gc[ts&1] -> c_new16 (full c_ts; also next step's c_old)
    {
      const u64* gsrc = (const u64*)(gc + (size_t)(ts & 1)*8192);
      for (int q = tid; q < 2048; q += 512) {
        int bb = q >> 6, k64 = q & 63;
        u64 v = __hip_atomic_load((u64*)gsrc + q, __ATOMIC_RELAXED, __HIP_MEMORY_SCOPE_AGENT);
        ((u64*)c_new16)[bb*66 + k64] = v;
      }
    }
    __syncthreads();

    // (E) o-peephole + h_new (role1). z-part order replicates R5 exactly.
    if (role == 1) {
      const uint4* wz  = s_w4 + 6*264 + j*33;                 // Wco
      const uint4* cn4 = (const uint4*)c_new16;
      float zacc[4];
#pragma unroll
      for (int p4 = 0; p4 < 4; ++p4) {
        float z0 = 0.f, z1 = 0.f;
#pragma unroll
        for (int q8 = 0; q8 < 8; ++q8) {
          int kc = p4*8 + q8;
          uint4 w  = wz[kc];
          uint4 cc = cn4[b*33 + kc];
          z0 = fd(w.x, cc.x, z0); z1 = fd(w.y, cc.y, z1);
          z0 = fd(w.z, cc.z, z0); z1 = fd(w.w, cc.w, z1);
        }
        zacc[p4] = z0 + z1;
      }
      float z = zacc[0] + zacc[1] + zacc[2] + zacc[3] + s_op[p] + s_bco[j];
      float o  = sigm(z);
      float hn = o * tanh_fast(s_cnf[p]);
      out[(size_t)(ts+1)*(NB*HID) + b*HID + n] = hn;
      __hip_atomic_store(&gh[b*256 + n], f2h_bits(hn),
                         __ATOMIC_RELAXED, __HIP_MEMORY_SCOPE_AGENT);
    }
    gbar3(arr, bid, (u32)(2*ts + 3));

    csw ^= 1;
  }
}

// ---------------- fallback (non-PRE) scan: R5 per-batch kernel --------------
__global__ __launch_bounds__(512, 2) void lstm_scan_np(
    const uint4* __restrict__ ws4, const float* __restrict__ x,
    const float* __restrict__ bx, const float* __restrict__ bh,
    const float* __restrict__ bci, const float* __restrict__ bcf,
    const float* __restrict__ bco, float* __restrict__ out)
{
  const int b = blockIdx.x, t = threadIdx.x;
  const uint4* WhT4  = ws4 + WH4_OFF;
  const uint4* WpT4  = ws4 + WP4_OFF;
  const uint4* WcoT4 = ws4 + WCO4_OFF;
  const uint4* WxT4  = ws4 + WX4_OFF;

  __shared__ __align__(16) uint4 s_wco[8192];
  __shared__ __align__(16) float s_i[256], s_f[256], s_g[256], s_op[256];
  __shared__ __align__(16) float s_c[256], s_cn[256], s_z[4][256];
  __shared__ __align__(16) u16 s_hh[256], s_cc[256], s_x[128];
  __shared__ float s_bci[256], s_bcf[256], s_bco[256];

  for (int i = t; i < 8192; i += 512) s_wco[i] = WcoT4[i];
  if (t < 256) {
    s_c[t] = 0.f; s_hh[t] = 0; s_cc[t] = 0;
    s_bci[t] = bci[t]; s_bcf[t] = bcf[t]; s_bco[t] = bco[t];
    out[b*HID + t] = 0.f;
    out[COFF + b*HID + t] = 0.f;
  }
  const int n1 = 512 + t;
  float biasA = bx[t] + bh[t], biasB = bx[n1] + bh[n1];
  __syncthreads();

  for (int ts = 0; ts < SEQ; ++ts) {
    if (t < 128) {
      const float* xr2 = x + (size_t)(b*SEQ + ts) * FIN;
      s_x[t] = f2h_bits(xr2[t]);
    }
    __syncthreads();

    float a0 = 0.f, a1 = 0.f, c0 = 0.f, c1 = 0.f;
#pragma unroll 4
    for (int kc = 0; kc < 32; ++kc) {
      uint4 wA = WhT4[kc*1024 + t];
      uint4 wB = WhT4[kc*1024 + n1];
      uint4 hh = *reinterpret_cast<const uint4*>(&s_hh[8*kc]);
      a0 = fd(wA.x, hh.x, a0); a1 = fd(wA.y, hh.y, a1);
      a0 = fd(wA.z, hh.z, a0); a1 = fd(wA.w, hh.w, a1);
      c0 = fd(wB.x, hh.x, c0); c1 = fd(wB.y, hh.y, c1);
      c0 = fd(wB.z, hh.z, c0); c1 = fd(wB.w, hh.w, c1);
    }
#pragma unroll 4
    for (int kc = 0; kc < 16; ++kc) {
      uint4 wA = WxT4[kc*1024 + t];
      uint4 wB = WxT4[kc*1024 + n1];
      uint4 xx = *reinterpret_cast<const uint4*>(&s_x[8*kc]);
      a0 = fd(wA.x, xx.x, a0); a1 = fd(wA.y, xx.y, a1);
      a0 = fd(wA.z, xx.z, a0); a1 = fd(wA.w, xx.w, a1);
      c0 = fd(wB.x, xx.x, c0); c1 = fd(wB.y, xx.y, c1);
      c0 = fd(wB.z, xx.z, c0); c1 = fd(wB.w, xx.w, c1);
    }
#pragma unroll 4
    for (int kc = 0; kc < 32; ++kc) {
      uint4 w  = WpT4[kc*512 + t];
      uint4 cc = *reinterpret_cast<const uint4*>(&s_cc[8*kc]);
      a0 = fd(w.x, cc.x, a0); a1 = fd(w.y, cc.y, a1);
      a0 = fd(w.z, cc.z, a0); a1 = fd(w.w, cc.w, a1);
    }
    float accA = a0 + a1 + biasA;
    float accB = c0 + c1 + biasB;

    int idx = t & 255;
    if (t < 256) { s_i[idx]  = sigm(accA + s_bci[idx]); s_op[idx] = accB; }
    else         { s_f[idx]  = sigm(accA + s_bcf[idx]); s_g[idx]  = tanh_fast(accB); }
    __syncthreads();

    if (t < 256) {
      float cn = s_f[t]*s_c[t] + s_i[t]*s_g[t];
      s_cn[t] = cn; s_c[t] = cn;
      s_cc[t] = f2h_bits(cn);
      out[COFF + (size_t)(ts+1)*(NB*HID) + b*HID + t] = cn;
    }
    __syncthreads();

    {
      int nn = t & 255, p0 = t >> 8;
      float z0 = 0.f, z1 = 0.f, z2 = 0.f, z3 = 0.f;
#pragma unroll
      for (int q8 = 0; q8 < 8; ++q8) {
        int kc = p0*8 + q8;
        uint4 w  = s_wco[kc*256 + nn];
        uint4 cc = *reinterpret_cast<const uint4*>(&s_cc[8*kc]);
        z0 = fd(w.x, cc.x, z0); z1 = fd(w.y, cc.y, z1);
        z0 = fd(w.z, cc.z, z0); z1 = fd(w.w, cc.w, z1);
      }
#pragma unroll
      for (int q8 = 0; q8 < 8; ++q8) {
        int kc = (p0+2)*8 + q8;
        uint4 w  = s_wco[kc*256 + nn];
        uint4 cc = *reinterpret_cast<const uint4*>(&s_cc[8*kc]);
        z2 = fd(w.x, cc.x, z2); z3 = fd(w.y, cc.y, z3);
        z2 = fd(w.z, cc.z, z2); z3 = fd(w.w, cc.w, z3);
      }
      s_z[p0][nn]   = z0 + z1;
      s_z[p0+2][nn] = z2 + z3;
    }
    __syncthreads();

    if (t < 256) {
      float z = s_z[0][t] + s_z[1][t] + s_z[2][t] + s_z[3][t]
              + s_op[t] + s_bco[t];
      float o  = sigm(z);
      float hn = o * tanh_fast(s_cn[t]);
      out[(size_t)(ts+1)*(NB*HID) + b*HID + t] = hn;
      s_hh[t] = f2h_bits(hn);
    }
    __syncthreads();
  }
}

// ---------------- launch ----------------------------------------------------
extern "C" void kernel_launch(void* const* d_in, const int* in_sizes, int n_in,
                              void* d_out, int out_size, void* d_ws, size_t ws_size,
                              hipStream_t stream)
{
  const float* x   = (const float*)d_in[0];
  const float* Wx  = (const float*)d_in[1];
  const float* bx  = (const float*)d_in[2];
  const float* Wh  = (const float*)d_in[3];
  const float* bh  = (const float*)d_in[4];
  const float* Wci = (const float*)d_in[5];
  const float* bci = (const float*)d_in[6];
  const float* Wcf = (const float*)d_in[7];
  const float* bcf = (const float*)d_in[8];
  const float* Wco = (const float*)d_in[9];
  const float* bco = (const float*)d_in[10];
  float* out = (float*)d_out;
  uint4* ws4 = (uint4*)d_ws;
  u16* xw  = (u16*)((char*)d_ws + (size_t)W4_TOTAL*16);

  char* exb = (char*)d_ws + EXB_BYTE;          // overlay on WxT4 (PRE only)
  u16* gh  = (u16*)(exb + GH_BYTE);
  u16* gc  = (u16*)(exb + GC_BYTE);
  u32* arr = (u32*)(exb + ARR_BYTE);

  const size_t NEED = (size_t)W4_TOTAL*16 + (size_t)SEQ*NB*G4*2;  // ~129 MB
  const bool pre = (ws_size >= NEED);   // constant across calls -> capture-safe

  hipLaunchKernelGGL(prep_weights, dim3((W4_TOTAL + 255)/256), dim3(256), 0, stream,
                     Wh, Wci, Wcf, Wco, Wx, ws4);
  if (pre) {
    hipLaunchKernelGGL(bar_reset, dim3(1), dim3(256), 0, stream, arr);
    hipLaunchKernelGGL(xw_gemm, dim3(4096, 16), dim3(256), 0, stream,
                       x, Wx, bx, bh, xw);
    hipLaunchKernelGGL(lstm_scan_p, dim3(NBLK), dim3(512), 0, stream,
                       ws4, xw, bci, bcf, bco, out, gh, gc, arr);
  } else {
    hipLaunchKernelGGL(lstm_scan_np, dim3(32), dim3(512), 0, stream,
                       ws4, x, bx, bh, bci, bcf, bco, out);
  }
}

// Round 9
// 6076.505 us; speedup vs baseline: 4.0288x; 2.8349x over previous
//
#include <hip/hip_runtime.h>
#include <cstdint>
#include <cstddef>

// FC_LSTM on MI355X — Round 13: K-split groups of 4, replicated state,
// ONE group-local sync per step. 3-tier fallback (ks -> R5 -> np).
// Evidence: R3/R4/R5: per-CU vmem ~16-18cyc/wave-instr (any width) -> per-CU
// L2 return ~60B/cyc; R5 streams 768KB/step = 13K cyc = the wall (11.87ms).
// R9-R12: 32-block grid barrier costs ~5-7K cyc EACH -> grid-sync dead.
// New: 128 blocks, 4 per batch (blocks b,b+32,b+64,b+96 = same XCD). Each
// streams only its 8-kc slice (192KB/step). h/c state REPLICATED in LDS per
// block (no state exchange); only 1024 f32 gate-partials exchanged, parity
// double-buffered, one 4-flag sync per step. Epilogue redundant in all 4
// blocks -> deterministic-identical state. UC ordering scheme = R12's
// (bit-exact proven). Numerics: 4-way partial reassociation vs R5.

typedef unsigned short u16;
typedef unsigned int   u32;
typedef unsigned long long u64;
typedef float  v4f __attribute__((ext_vector_type(4)));
typedef short  v8s __attribute__((ext_vector_type(8)));
typedef _Float16 h2 __attribute__((ext_vector_type(2)));

#define SEQ 2048
#define NB  32
#define HID 256
#define G4  1024
#define FIN 128
#define COFF (2049*NB*HID)   // element offset of memorys half of d_out

// uint4-unit offsets in ws
#define WH4_OFF  0        // [32][1024] : chunk kc (k=8kc..8kc+7), row n
#define WP4_OFF  32768    // [32][512]  : rows = [Wci n | Wcf n+256]
#define WCO4_OFF 49152    // [32][256]
#define WX4_OFF  57344    // [16][1024] (np fallback weights; flag overlay for ks)
#define W4_TOTAL 73728    // uint4 count (1.125 MB)

// ks-tier flag overlay inside the WxT4 region (np never runs concurrently)
#define EXB_BYTE  ((size_t)WX4_OFF * 16)
// flags: u32 fl[(sl*32+b)*64], 128 slots * 256B = 32 KB

#define XW_BYTES  ((size_t)SEQ*NB*G4*2)      // 128 MB
// gp partials: f32 gp[2 parity][4 slice][32 batch][1024], 1 MB, after xw

// R5-tier register-cache depths (historic; compiler remats them, measured ok)
#define CWH 14
#define CWP 8

__device__ __forceinline__ u16 f2bf(float f) {
  u32 u = __builtin_bit_cast(u32, f);
  u32 r = (u + 0x7fffu + ((u >> 16) & 1u)) >> 16;
  return (u16)r;
}
__device__ __forceinline__ u16 f2h_bits(float f) {
  _Float16 h = (_Float16)f;
  return __builtin_bit_cast(u16, h);
}
__device__ __forceinline__ u32 pack2f(float a, float b) {
  u32 lo = f2h_bits(a);
  u32 hi = f2h_bits(b);
  return lo | (hi << 16);
}
__device__ __forceinline__ float fd(u32 w, u32 u, float acc) {
  h2 hw = __builtin_bit_cast(h2, w);
  h2 hu = __builtin_bit_cast(h2, u);
  return __builtin_amdgcn_fdot2(hw, hu, acc, false);
}
__device__ __forceinline__ float sigm(float v) { return 1.f / (1.f + __expf(-v)); }
__device__ __forceinline__ float tanh_fast(float x) {
  float xx = fminf(fmaxf(x, -15.f), 15.f);
  float e = __expf(2.f * xx);
  return (e - 1.f) / (e + 1.f);
}

// ---------------- Phase 0: weight repack (f32 -> f16 x8 chunks) -------------
__global__ __launch_bounds__(256) void prep_weights(
    const float* __restrict__ Wh, const float* __restrict__ Wci,
    const float* __restrict__ Wcf, const float* __restrict__ Wco,
    const float* __restrict__ Wx, uint4* __restrict__ ws4)
{
  int i = blockIdx.x * 256 + threadIdx.x;
  if (i >= W4_TOTAL) return;
  const float* src;
  if (i < WP4_OFF) {                       // WhT4
    int kc = i >> 10, n = i & 1023;
    src = Wh + n*256 + kc*8;
  } else if (i < WCO4_OFF) {               // WpT4
    int l = i - WP4_OFF; int kc = l >> 9, n = l & 511;
    src = ((n < 256) ? (Wci + n*256) : (Wcf + (n-256)*256)) + kc*8;
  } else if (i < WX4_OFF) {                // WcoT4
    int l = i - WCO4_OFF; int kc = l >> 8, n = l & 255;
    src = Wco + n*256 + kc*8;
  } else {                                 // WxT4 (np fallback)
    int l = i - WX4_OFF; int kc = l >> 10, n = l & 1023;
    src = Wx + n*128 + kc*8;
  }
  uint4 r;
  r.x = pack2f(src[0], src[1]);
  r.y = pack2f(src[2], src[3]);
  r.z = pack2f(src[4], src[5]);
  r.w = pack2f(src[6], src[7]);
  ws4[i] = r;
}

// ---------------- flag reset (graph-replay safe) ----------------------------
__global__ __launch_bounds__(256) void bar_reset(u32* __restrict__ fl) {
  for (int i = threadIdx.x; i < 128*64; i += 256) fl[i] = 0u;
}

// ---------------- Phase 1: xw GEMM (bf16 MFMA, f32 inputs) ------------------
__global__ __launch_bounds__(256) void xw_gemm(
    const float* __restrict__ x, const float* __restrict__ Wx,
    const float* __restrict__ bx, const float* __restrict__ bh,
    u16* __restrict__ xw)
{
  int wave = threadIdx.x >> 6, lane = threadIdx.x & 63;
  int s = lane & 15, q = lane >> 4;
  int mtile = blockIdx.x;              // 0..4095
  int ntile = blockIdx.y * 4 + wave;   // 0..63
  const float* xa = x  + (size_t)(mtile*16 + s) * 128 + q*8;
  const float* wb = Wx + (size_t)(ntile*16 + s) * 128 + q*8;
  v4f acc = {0.f, 0.f, 0.f, 0.f};
#pragma unroll
  for (int ko = 0; ko < 4; ++ko) {
    float4 a0 = *reinterpret_cast<const float4*>(xa + ko*32);
    float4 a1 = *reinterpret_cast<const float4*>(xa + ko*32 + 4);
    float4 b0 = *reinterpret_cast<const float4*>(wb + ko*32);
    float4 b1 = *reinterpret_cast<const float4*>(wb + ko*32 + 4);
    v8s a, b;
    a[0]=(short)f2bf(a0.x); a[1]=(short)f2bf(a0.y); a[2]=(short)f2bf(a0.z); a[3]=(short)f2bf(a0.w);
    a[4]=(short)f2bf(a1.x); a[5]=(short)f2bf(a1.y); a[6]=(short)f2bf(a1.z); a[7]=(short)f2bf(a1.w);
    b[0]=(short)f2bf(b0.x); b[1]=(short)f2bf(b0.y); b[2]=(short)f2bf(b0.z); b[3]=(short)f2bf(b0.w);
    b[4]=(short)f2bf(b1.x); b[5]=(short)f2bf(b1.y); b[6]=(short)f2bf(b1.z); b[7]=(short)f2bf(b1.w);
    acc = __builtin_amdgcn_mfma_f32_16x16x32_bf16(a, b, acc, 0, 0, 0);
  }
  int n = ntile*16 + s;
  float bias = bx[n] + bh[n];
#pragma unroll
  for (int p = 0; p < 4; ++p) {
    int m = mtile*16 + q*4 + p;
    int bb = m >> 11, t = m & 2047;   // r = b*2048 + t
    xw[(size_t)(t*NB + bb) * G4 + n] = f2h_bits(acc[p] + bias);
  }
}

// ---------------- Phase 2 (ks): K-split group-of-4 scan ---------------------
// 128 blocks: slice s = blockIdx.x>>5 (kc in [8s,8s+8)), batch b = blockIdx.x&31.
// Group {b, 32+b, 64+b, 96+b} -> same XCD (round-robin %8). 512 threads:
// thread t owns gate rows n0=t (i/f) and n1=512+t (o/g), exactly R5's map.
// State (h,c) REPLICATED per block in LDS; only gate partials exchanged.
__global__ __launch_bounds__(512) void lstm_scan_ks(
    const uint4* __restrict__ ws4, const u16* __restrict__ xw,
    const float* __restrict__ bci, const float* __restrict__ bcf,
    const float* __restrict__ bco, float* __restrict__ out,
    float* __restrict__ gp, u32* __restrict__ fl)
{
  const int t   = threadIdx.x;
  const int s   = blockIdx.x >> 5;     // slice 0..3
  const int b   = blockIdx.x & 31;     // batch
  const int n1  = 512 + t;
  const int kc0 = s * 8;

  const uint4* WhT4  = ws4 + WH4_OFF;
  const uint4* WpT4  = ws4 + WP4_OFF;
  const uint4* WcoT4 = ws4 + WCO4_OFF;

  __shared__ __align__(16) uint4 s_wco[8192];   // 128 KB, full Wco
  __shared__ __align__(16) float s_i[256], s_f[256], s_g[256], s_op[256];
  __shared__ __align__(16) float s_c[256], s_cn[256], s_z[4][256];
  __shared__ __align__(16) u16 s_hh[256];   // f16 h (replicated state)
  __shared__ __align__(16) u16 s_cc[256];   // f16 c
  __shared__ float s_bci[256], s_bcf[256], s_bco[256];

  for (int i = t; i < 8192; i += 512) s_wco[i] = WcoT4[i];
  if (t < 256) {
    s_c[t] = 0.f; s_hh[t] = 0; s_cc[t] = 0;
    s_bci[t] = bci[t]; s_bcf[t] = bcf[t]; s_bco[t] = bco[t];
    if (s == 0) {
      out[b*HID + t] = 0.f;          // h0
      out[COFF + b*HID + t] = 0.f;   // c0
    }
  }
  __syncthreads();

  for (int ts = 0; ts < SEQ; ++ts) {
    const int par = ts & 1;
    // xw prefetch (same columns as R5: n0 for accA, n1 for accB)
    const u16* xr = xw + ((size_t)ts*NB + b) * G4;
    u16 xwa = xr[t];
    u16 xwb = xr[n1];

    // ---- partial dots over own kc slice (streams 192KB from L2) ----
    float a0 = 0.f, a1 = 0.f, c0 = 0.f, c1 = 0.f;
#pragma unroll
    for (int k = 0; k < 8; ++k) {
      int kc = kc0 + k;
      uint4 wA = WhT4[kc*1024 + t];
      uint4 wB = WhT4[kc*1024 + n1];
      uint4 hh = *reinterpret_cast<const uint4*>(&s_hh[8*kc]);
      a0 = fd(wA.x, hh.x, a0); a1 = fd(wA.y, hh.y, a1);
      a0 = fd(wA.z, hh.z, a0); a1 = fd(wA.w, hh.w, a1);
      c0 = fd(wB.x, hh.x, c0); c1 = fd(wB.y, hh.y, c1);
      c0 = fd(wB.z, hh.z, c0); c1 = fd(wB.w, hh.w, c1);
    }
#pragma unroll
    for (int k = 0; k < 8; ++k) {
      int kc = kc0 + k;
      uint4 w  = WpT4[kc*512 + t];
      uint4 cc = *reinterpret_cast<const uint4*>(&s_cc[8*kc]);
      a0 = fd(w.x, cc.x, a0); a1 = fd(w.y, cc.y, a1);
      a0 = fd(w.z, cc.z, a0); a1 = fd(w.w, cc.w, a1);
    }
    float pA = a0 + a1;
    float pB = c0 + c1;

    // ---- publish partials (relaxed UC; parity buffer) ----
    {
      u32* dst = (u32*)(gp + ((size_t)(par*4 + s)*32 + b)*1024);
      __hip_atomic_store(dst + t,   __builtin_bit_cast(u32, pA),
                         __ATOMIC_RELAXED, __HIP_MEMORY_SCOPE_AGENT);
      __hip_atomic_store(dst + n1,  __builtin_bit_cast(u32, pB),
                         __ATOMIC_RELAXED, __HIP_MEMORY_SCOPE_AGENT);
    }

    // ---- ONE group sync: drain stores, flag, poll 4 group flags ----
    __syncthreads();                      // vmcnt(0) in every wave
    asm volatile("" ::: "memory");
    if (t == 0)
      __hip_atomic_store(&fl[(s*32 + b)*64], (u32)(ts + 1),
                         __ATOMIC_RELAXED, __HIP_MEMORY_SCOPE_AGENT);
    if (t < 4) {
      u32* slot = &fl[(t*32 + b)*64];
      while (__hip_atomic_load(slot, __ATOMIC_RELAXED, __HIP_MEMORY_SCOPE_AGENT)
             < (u32)(ts + 1))
        __builtin_amdgcn_s_sleep(1);
    }
    asm volatile("" ::: "memory");
    __syncthreads();

    // ---- combine (identical formula in all 4 blocks; slice order 0..3) ----
    float pa[4], pb[4];
#pragma unroll
    for (int sl = 0; sl < 4; ++sl) {
      if (sl == s) { pa[sl] = pA; pb[sl] = pB; }
      else {
        const u32* src = (const u32*)(gp + ((size_t)(par*4 + sl)*32 + b)*1024);
        u32 va = __hip_atomic_load(src + t,  __ATOMIC_RELAXED, __HIP_MEMORY_SCOPE_AGENT);
        u32 vb = __hip_atomic_load(src + n1, __ATOMIC_RELAXED, __HIP_MEMORY_SCOPE_AGENT);
        pa[sl] = __builtin_bit_cast(float, va);
        pb[sl] = __builtin_bit_cast(float, vb);
      }
    }
    float accA = ((pa[0] + pa[1]) + pa[2]) + pa[3];
    float accB = ((pb[0] + pb[1]) + pb[2]) + pb[3];
    accA += (float)__builtin_bit_cast(_Float16, xwa);
    accB += (float)__builtin_bit_cast(_Float16, xwb);

    // ---- epilogue (R5 code, redundant in all 4 blocks) ----
    int idx = t & 255;
    if (t < 256) { s_i[idx]  = sigm(accA + s_bci[idx]); s_op[idx] = accB; }
    else         { s_f[idx]  = sigm(accA + s_bcf[idx]); s_g[idx]  = tanh_fast(accB); }
    __syncthreads();

    if (t < 256) {
      float cn = s_f[t]*s_c[t] + s_i[t]*s_g[t];
      s_cn[t] = cn; s_c[t] = cn;
      s_cc[t] = f2h_bits(cn);
      if (s == 0)
        out[COFF + (size_t)(ts+1)*(NB*HID) + b*HID + t] = cn;
    }
    __syncthreads();

    {   // z = Wco . c_new from LDS; R5's 512-thread 4-part split
      int nn = t & 255, p0 = t >> 8;
      float z0 = 0.f, z1 = 0.f, z2 = 0.f, z3 = 0.f;
#pragma unroll
      for (int q8 = 0; q8 < 8; ++q8) {
        int kc = p0*8 + q8;
        uint4 w  = s_wco[kc*256 + nn];
        uint4 cc = *reinterpret_cast<const uint4*>(&s_cc[8*kc]);
        z0 = fd(w.x, cc.x, z0); z1 = fd(w.y, cc.y, z1);
        z0 = fd(w.z, cc.z, z0); z1 = fd(w.w, cc.w, z1);
      }
#pragma unroll
      for (int q8 = 0; q8 < 8; ++q8) {
        int kc = (p0+2)*8 + q8;
        uint4 w  = s_wco[kc*256 + nn];
        uint4 cc = *reinterpret_cast<const uint4*>(&s_cc[8*kc]);
        z2 = fd(w.x, cc.x, z2); z3 = fd(w.y, cc.y, z3);
        z2 = fd(w.z, cc.z, z2); z3 = fd(w.w, cc.w, z3);
      }
      s_z[p0][nn]   = z0 + z1;
      s_z[p0+2][nn] = z2 + z3;
    }
    __syncthreads();

    if (t < 256) {
      float z = s_z[0][t] + s_z[1][t] + s_z[2][t] + s_z[3][t]
              + s_op[t] + s_bco[t];
      float o  = sigm(z);
      float hn = o * tanh_fast(s_cn[t]);
      if (s == 0)
        out[(size_t)(ts+1)*(NB*HID) + b*HID + t] = hn;
      s_hh[t] = f2h_bits(hn);
    }
    __syncthreads();
  }
}

// ---------------- Phase 2 (R5 tier / np tier): per-batch scan ---------------
template<bool PRE>
__global__ __launch_bounds__(512, 2) void lstm_scan_r5(
    const uint4* __restrict__ ws4, const void* __restrict__ xsrc_v,
    const float* __restrict__ bx, const float* __restrict__ bh,
    const float* __restrict__ bci, const float* __restrict__ bcf,
    const float* __restrict__ bco, float* __restrict__ out)
{
  const int b = blockIdx.x, t = threadIdx.x;
  const uint4* WhT4  = ws4 + WH4_OFF;
  const uint4* WpT4  = ws4 + WP4_OFF;
  const uint4* WcoT4 = ws4 + WCO4_OFF;
  const uint4* WxT4  = ws4 + WX4_OFF;

  __shared__ __align__(16) uint4 s_wco[8192];
  __shared__ __align__(16) float s_i[256], s_f[256], s_g[256], s_op[256];
  __shared__ __align__(16) float s_c[256], s_cn[256], s_z[4][256];
  __shared__ __align__(16) u16 s_hh[256], s_cc[256], s_x[128];
  __shared__ float s_bci[256], s_bcf[256], s_bco[256];

  for (int i = t; i < 8192; i += 512) s_wco[i] = WcoT4[i];
  if (t < 256) {
    s_c[t] = 0.f; s_hh[t] = 0; s_cc[t] = 0;
    s_bci[t] = bci[t]; s_bcf[t] = bcf[t]; s_bco[t] = bco[t];
    out[b*HID + t] = 0.f;
    out[COFF + b*HID + t] = 0.f;
  }
  const int n1 = 512 + t;
  float biasA = 0.f, biasB = 0.f;
  if (!PRE) { biasA = bx[t] + bh[t]; biasB = bx[n1] + bh[n1]; }

  uint4 whA[CWH], whB[CWH], wpA[CWP];
#pragma unroll
  for (int kc = 0; kc < CWH; ++kc) {
    whA[kc] = WhT4[kc*1024 + t];
    whB[kc] = WhT4[kc*1024 + n1];
  }
#pragma unroll
  for (int kc = 0; kc < CWP; ++kc) wpA[kc] = WpT4[kc*512 + t];

  __syncthreads();

  const u16* xw = (const u16*)xsrc_v;

  for (int ts = 0; ts < SEQ; ++ts) {
    u16 xw0 = 0, xw1 = 0;
    if (PRE) {
      const u16* xr = xw + (size_t)(ts*NB + b) * G4;
      xw0 = xr[t]; xw1 = xr[n1];
    } else {
      if (t < 128) {
        const float* xr2 = (const float*)xsrc_v + (size_t)(b*SEQ + ts) * FIN;
        s_x[t] = f2h_bits(xr2[t]);
      }
      __syncthreads();
    }

    float a0 = 0.f, a1 = 0.f, c0 = 0.f, c1 = 0.f;
#pragma unroll
    for (int kc = 0; kc < CWH; ++kc) {
      uint4 hh = *reinterpret_cast<const uint4*>(&s_hh[8*kc]);
      a0 = fd(whA[kc].x, hh.x, a0); a1 = fd(whA[kc].y, hh.y, a1);
      a0 = fd(whA[kc].z, hh.z, a0); a1 = fd(whA[kc].w, hh.w, a1);
      c0 = fd(whB[kc].x, hh.x, c0); c1 = fd(whB[kc].y, hh.y, c1);
      c0 = fd(whB[kc].z, hh.z, c0); c1 = fd(whB[kc].w, hh.w, c1);
    }
#pragma unroll 4
    for (int kc = CWH; kc < 32; ++kc) {
      uint4 wA = WhT4[kc*1024 + t];
      uint4 wB = WhT4[kc*1024 + n1];
      uint4 hh = *reinterpret_cast<const uint4*>(&s_hh[8*kc]);
      a0 = fd(wA.x, hh.x, a0); a1 = fd(wA.y, hh.y, a1);
      a0 = fd(wA.z, hh.z, a0); a1 = fd(wA.w, hh.w, a1);
      c0 = fd(wB.x, hh.x, c0); c1 = fd(wB.y, hh.y, c1);
      c0 = fd(wB.z, hh.z, c0); c1 = fd(wB.w, hh.w, c1);
    }
    if (!PRE) {
#pragma unroll 4
      for (int kc = 0; kc < 16; ++kc) {
        uint4 wA = WxT4[kc*1024 + t];
        uint4 wB = WxT4[kc*1024 + n1];
        uint4 xx = *reinterpret_cast<const uint4*>(&s_x[8*kc]);
        a0 = fd(wA.x, xx.x, a0); a1 = fd(wA.y, xx.y, a1);
        a0 = fd(wA.z, xx.z, a0); a1 = fd(wA.w, xx.w, a1);
        c0 = fd(wB.x, xx.x, c0); c1 = fd(wB.y, xx.y, c1);
        c0 = fd(wB.z, xx.z, c0); c1 = fd(wB.w, xx.w, c1);
      }
    }
#pragma unroll
    for (int kc = 0; kc < CWP; ++kc) {
      uint4 cc = *reinterpret_cast<const uint4*>(&s_cc[8*kc]);
      a0 = fd(wpA[kc].x, cc.x, a0); a1 = fd(wpA[kc].y, cc.y, a1);
      a0 = fd(wpA[kc].z, cc.z, a0); a1 = fd(wpA[kc].w, cc.w, a1);
    }
#pragma unroll 4
    for (int kc = CWP; kc < 32; ++kc) {
      uint4 w  = WpT4[kc*512 + t];
      uint4 cc = *reinterpret_cast<const uint4*>(&s_cc[8*kc]);
      a0 = fd(w.x, cc.x, a0); a1 = fd(w.y, cc.y, a1);
      a0 = fd(w.z, cc.z, a0); a1 = fd(w.w, cc.w, a1);
    }

    float accA = a0 + a1;
    float accB = c0 + c1;
    if (PRE) {
      accA += (float)__builtin_bit_cast(_Float16, xw0);
      accB += (float)__builtin_bit_cast(_Float16, xw1);
    } else {
      accA += biasA;
      accB += biasB;
    }

    int idx = t & 255;
    if (t < 256) { s_i[idx]  = sigm(accA + s_bci[idx]); s_op[idx] = accB; }
    else         { s_f[idx]  = sigm(accA + s_bcf[idx]); s_g[idx]  = tanh_fast(accB); }
    __syncthreads();

    if (t < 256) {
      float cn = s_f[t]*s_c[t] + s_i[t]*s_g[t];
      s_cn[t] = cn; s_c[t] = cn;
      s_cc[t] = f2h_bits(cn);
      out[COFF + (size_t)(ts+1)*(NB*HID) + b*HID + t] = cn;
    }
    __syncthreads();

    {
      int nn = t & 255, p0 = t >> 8;
      float z0 = 0.f, z1 = 0.f, z2 = 0.f, z3 = 0.f;
#pragma unroll
      for (int q8 = 0; q8 < 8; ++q8) {
        int kc = p0*8 + q8;
        uint4 w  = s_wco[kc*256 + nn];
        uint4 cc = *reinterpret_cast<const uint4*>(&s_cc[8*kc]);
        z0 = fd(w.x, cc.x, z0); z1 = fd(w.y, cc.y, z1);
        z0 = fd(w.z, cc.z, z0); z1 = fd(w.w, cc.w, z1);
      }
#pragma unroll
      for (int q8 = 0; q8 < 8; ++q8) {
        int kc = (p0+2)*8 + q8;
        uint4 w  = s_wco[kc*256 + nn];
        uint4 cc = *reinterpret_cast<const uint4*>(&s_cc[8*kc]);
        z2 = fd(w.x, cc.x, z2); z3 = fd(w.y, cc.y, z3);
        z2 = fd(w.z, cc.z, z2); z3 = fd(w.w, cc.w, z3);
      }
      s_z[p0][nn]   = z0 + z1;
      s_z[p0+2][nn] = z2 + z3;
    }
    __syncthreads();

    if (t < 256) {
      float z = s_z[0][t] + s_z[1][t] + s_z[2][t] + s_z[3][t]
              + s_op[t] + s_bco[t];
      float o  = sigm(z);
      float hn = o * tanh_fast(s_cn[t]);
      out[(size_t)(ts+1)*(NB*HID) + b*HID + t] = hn;
      s_hh[t] = f2h_bits(hn);
    }
    __syncthreads();
  }
}

// ---------------- launch ----------------------------------------------------
extern "C" void kernel_launch(void* const* d_in, const int* in_sizes, int n_in,
                              void* d_out, int out_size, void* d_ws, size_t ws_size,
                              hipStream_t stream)
{
  const float* x   = (const float*)d_in[0];
  const float* Wx  = (const float*)d_in[1];
  const float* bx  = (const float*)d_in[2];
  const float* Wh  = (const float*)d_in[3];
  const float* bh  = (const float*)d_in[4];
  const float* Wci = (const float*)d_in[5];
  const float* bci = (const float*)d_in[6];
  const float* Wcf = (const float*)d_in[7];
  const float* bcf = (const float*)d_in[8];
  const float* Wco = (const float*)d_in[9];
  const float* bco = (const float*)d_in[10];
  float* out = (float*)d_out;
  uint4* ws4 = (uint4*)d_ws;
  u16* xw  = (u16*)((char*)d_ws + (size_t)W4_TOTAL*16);

  const size_t NEED1 = (size_t)W4_TOTAL*16 + XW_BYTES;          // R5 tier (~129MB)
  const size_t NEED2 = NEED1 + (size_t)2*4*32*1024*4;           // + 1MB partials
  float* gp = (float*)((char*)d_ws + NEED1);
  u32*   fl = (u32*)((char*)d_ws + EXB_BYTE);                   // WxT4 overlay

  const bool ks  = (ws_size >= NEED2);   // constant across calls -> capture-safe
  const bool pre = (ws_size >= NEED1);

  hipLaunchKernelGGL(prep_weights, dim3((W4_TOTAL + 255)/256), dim3(256), 0, stream,
                     Wh, Wci, Wcf, Wco, Wx, ws4);
  if (ks) {
    hipLaunchKernelGGL(bar_reset, dim3(1), dim3(256), 0, stream, fl);
    hipLaunchKernelGGL(xw_gemm, dim3(4096, 16), dim3(256), 0, stream,
                       x, Wx, bx, bh, xw);
    hipLaunchKernelGGL(lstm_scan_ks, dim3(128), dim3(512), 0, stream,
                       ws4, xw, bci, bcf, bco, out, gp, fl);
  } else if (pre) {
    hipLaunchKernelGGL(xw_gemm, dim3(4096, 16), dim3(256), 0, stream,
                       x, Wx, bx, bh, xw);
    hipLaunchKernelGGL((lstm_scan_r5<true>), dim3(32), dim3(512), 0, stream,
                       ws4, (const void*)xw, bx, bh, bci, bcf, bco, out);
  } else {
    hipLaunchKernelGGL((lstm_scan_r5<false>), dim3(32), dim3(512), 0, stream,
                       ws4, (const void*)x, bx, bh, bci, bcf, bco, out);
  }
}